// Round 8
// baseline (187.553 us; speedup 1.0000x reference)
//
#include <hip/hip_runtime.h>
#include <stdint.h>

typedef unsigned short u16;
typedef unsigned int   u32;
typedef __attribute__((ext_vector_type(8))) short short8;
typedef __attribute__((ext_vector_type(4))) float f32x4;
typedef __attribute__((ext_vector_type(8))) u16   u16x8;
typedef __attribute__((ext_vector_type(4))) u16   u16x4;

// Problem constants: N=4, S=4096, E=1024, H=16, D=64
static constexpr size_t NX = (size_t)4 * 4096 * 1024;   // 16,777,216 x elems
static constexpr size_t NW = (size_t)1024 * 1024;       // 1,048,576 weight elems

// Workspace layout (bytes).
// OFF_XB: xb bf16 33.5MB, later En f32 16.8MB (xb dead after gemm_vs).
// OFF_QK: QKb bf16 67MB, later G bf16 33.5MB (QKb dead after energy).
static constexpr size_t OFF_XB   = 0;
static constexpr size_t OFF_EN   = 0;
static constexpr size_t OFF_QK   = 33554432;
static constexpr size_t OFF_WQB  = 100663296;           // 2,097,152 (Wkb contiguous after)
static constexpr size_t OFF_WKB  = 102760448;           // 2,097,152
static constexpr size_t OFF_WOB  = 104857600;           // 2,097,152
static constexpr size_t OFF_WVST = 106954752;           // 131,072  bf16 Bvs [64][1024]
static constexpr size_t OFF_VS   = 107216896;           // 2,097,152 bf16 Vsb [16384][64]
static constexpr size_t OFF_GMAX = 111411200;           // 4,096
static constexpr size_t OFF_INVZ = 111415296;           // 4,096
static constexpr size_t OFF_ST   = 111419392;           // pmax 256KB + psum 256KB

static __device__ __forceinline__ u16 f2bf(float f) {
    u32 u = __builtin_bit_cast(u32, f);
    u += 0x7fffu + ((u >> 16) & 1u);        // RNE
    return (u16)(u >> 16);
}
static __device__ __forceinline__ float bf2f(u16 v) {
    u32 u = ((u32)v) << 16;
    return __builtin_bit_cast(float, u);
}

#if __has_builtin(__builtin_amdgcn_global_load_lds)
#define HAVE_GLOAD_LDS 1
static __device__ __forceinline__ void gload_lds16(const void* g, void* l) {
    __builtin_amdgcn_global_load_lds(
        (__attribute__((address_space(1))) void*)(uintptr_t)g,
        (__attribute__((address_space(3))) void*)(uintptr_t)l,
        16, 0, 0);
}
#endif

#if __has_builtin(__builtin_amdgcn_sched_barrier)
#define SCHED_FENCE() __builtin_amdgcn_sched_barrier(0)
#else
#define SCHED_FENCE()
#endif
#define SBAR()   __builtin_amdgcn_s_barrier()
#define VMCNT4() do { asm volatile("s_waitcnt vmcnt(4)" ::: "memory"); } while (0)
#define VMCNT0() do { asm volatile("s_waitcnt vmcnt(0)" ::: "memory"); } while (0)
#define LGKM0()  do { asm volatile("s_waitcnt lgkmcnt(0)" ::: "memory"); } while (0)

// ---------------------------------------------------------------------------
// fused fp32 -> bf16 conversion for x, Wq, Wk, Wo
__global__ __launch_bounds__(256)
void cvt_kernel(const float* __restrict__ x, const float* __restrict__ wq,
                const float* __restrict__ wk, const float* __restrict__ wo,
                u16* __restrict__ xb, u16* __restrict__ wqb,
                u16* __restrict__ wkb, u16* __restrict__ wob)
{
    size_t i = ((size_t)blockIdx.x * 256 + threadIdx.x) * 8;
    const float* s; u16* dst; size_t o;
    if (i < NX) { s = x; dst = xb; o = i; }
    else {
        size_t r = i - NX;
        int w = (int)(r >> 20);             // NW = 2^20
        o = r & (NW - 1);
        s   = (w == 0) ? wq  : (w == 1) ? wk  : wo;
        dst = (w == 0) ? wqb : (w == 1) ? wkb : wob;
    }
    f32x4 a = *(const f32x4*)&s[o];
    f32x4 c = *(const f32x4*)&s[o + 4];
    u16x8 v;
    v[0]=f2bf(a[0]); v[1]=f2bf(a[1]); v[2]=f2bf(a[2]); v[3]=f2bf(a[3]);
    v[4]=f2bf(c[0]); v[5]=f2bf(c[1]); v[6]=f2bf(c[2]); v[7]=f2bf(c[3]);
    *(u16x8*)&dst[o] = v;
}

// Bvs[d][e] = bf16( sum_h Wv[(h*64+d)*1024 + e] )   (B^T layout for gemm_vs)
__global__ __launch_bounds__(256)
void wvst_kernel(const float* __restrict__ Wv, u16* __restrict__ Bvs)
{
    int idx = blockIdx.x * 256 + threadIdx.x;   // 65536 total
    int d = idx >> 10;
    int e = idx & 1023;
    float s = 0.f;
    #pragma unroll
    for (int h = 0; h < 16; ++h) s += Wv[(size_t)(h * 64 + d) * 1024 + e];
    Bvs[(size_t)d * 1024 + e] = f2bf(s);
}

// ---------------------------------------------------------------------------
// 256x256-tile 8-wave bf16 GEMM — faithful m201 8-phase schedule (T1..T5).
// C[m][o] = sum_k A[m][k]*B[o][k]  (B^T layout), BK=64, 512 threads.
// LDS 128KB = 8 slots of 16KB: A slots [(p*2+h)<<13], B at +32768.
// Half-tiles: h0=A-up(rows 0..127), h1=A-low, h2=B-up(cols 0..127), h3=B-low.
// Per tile t, 4 phases (quadrants of each wave's 128x64 output):
//   q0: read af03+bf01 (12 ds) | stage H(t+1,h2) | SBAR lgkm0 | 16 MFMA | SBAR
//   q1: read af47+bf23 (12 ds) | stage H(t+1,h3) | SBAR lgkm0 | 16 MFMA | SBAR
//   q2:                          stage H(t+2,h0) | SBAR       | 16 MFMA | SBAR
//   q3:                          stage H(t+2,h1) | vmcnt(4) SBAR | 16 MFMA | SBAR
// vmcnt(4) leaves exactly the 2 H(t+2,*) half-tiles (4 loads) in flight and
// drains H(t+1,*) -> tile t+1 resident before its q0 reads. FIFO-verified.
// Overwrite safety: every slot's last ds_read drains (lgkm0) >=1 barrier
// before the overwriting stage issues.
__global__ __launch_bounds__(512, 2)
void gemm_qk(const u16* __restrict__ A, const u16* __restrict__ Bw,
             u16* __restrict__ C, int M, int N, int K, int lognbx)
{
    __shared__ u16 lds[65536];
    const int tid  = threadIdx.x;
    const int wave = tid >> 6;
    const int lane = tid & 63;

    // T1: XCD-bijective swizzle (gridDim.x % 8 == 0)
    const int nwg = gridDim.x;
    const int swz = ((int)blockIdx.x & 7) * (nwg >> 3) + ((int)blockIdx.x >> 3);
    const long col0 = (long)(swz & ((1 << lognbx) - 1)) * 256;
    const long row0 = (long)(swz >> lognbx) * 256;

    const int wr2 = wave >> 2;              // 0..1 wave row half
    const int wc2 = wave & 3;               // 0..3 wave col quarter
    const int fr  = lane & 15;
    const int kq  = lane >> 4;
    const int rx  = fr & 7;

    const u16* Abase = A  + row0 * K;
    const u16* Bbase = Bw + col0 * K;

    auto STAGE_A = [&](int t, int h) {
        u16* slot = &lds[(((t & 1) << 1) | h) << 13];
        const u16* src = Abase + (size_t)(h * 128) * K + ((size_t)t << 6);
        #pragma unroll
        for (int l = 0; l < 2; ++l) {
            const int G = wave * 128 + l * 64 + lane;
            const int rr = G >> 3;
            const int gs = (G & 7) ^ (rr & 7);
#ifdef HAVE_GLOAD_LDS
            gload_lds16(src + (size_t)rr * K + gs * 8, slot + wave * 1024 + l * 512);
#else
            *(short8*)&slot[G * 8] = *(const short8*)(src + (size_t)rr * K + gs * 8);
#endif
        }
    };
    auto STAGE_B = [&](int t, int h) {
        u16* slot = &lds[32768 + ((((t & 1) << 1) | h) << 13)];
        const u16* src = Bbase + (size_t)(h * 128) * K + ((size_t)t << 6);
        #pragma unroll
        for (int l = 0; l < 2; ++l) {
            const int G = wave * 128 + l * 64 + lane;
            const int rr = G >> 3;
            const int gs = (G & 7) ^ (rr & 7);
#ifdef HAVE_GLOAD_LDS
            gload_lds16(src + (size_t)rr * K + gs * 8, slot + wave * 1024 + l * 512);
#else
            *(short8*)&slot[G * 8] = *(const short8*)(src + (size_t)rr * K + gs * 8);
#endif
        }
    };

    auto LDA = [&](int t, int m, int kk) -> short8 {   // m 0..7 across wave's 128 rows
        const u16* slot = &lds[(((t & 1) << 1) | wr2) << 13];
        const int rr = m * 16 + fr;
        return *(const short8*)&slot[rr * 64 + ((((kk << 2) | kq)) ^ rx) * 8];
    };
    auto LDB = [&](int t, int n, int kk) -> short8 {   // n 0..3 across wave's 64 cols
        const u16* slot = &lds[32768 + ((((t & 1) << 1) | (wc2 >> 1)) << 13)];
        const int rr = (wc2 & 1) * 64 + n * 16 + fr;
        return *(const short8*)&slot[rr * 64 + ((((kk << 2) | kq)) ^ rx) * 8];
    };

    f32x4 acc[8][4] = {};
    short8 af03[4][2], af47[4][2], bf01[2][2], bf23[2][2];

    // prologue: H(0,0..3), H(1,0), H(1,1); vmcnt(4) -> tile 0 resident
    STAGE_A(0, 0); STAGE_A(0, 1); STAGE_B(0, 0); STAGE_B(0, 1);
    STAGE_A(1, 0); STAGE_A(1, 1);
    VMCNT4();
    SBAR();

    const int nt = K >> 6;
    for (int t = 0; t < nt; ++t) {
        // ===== q0: reads af03,bf01 | stage H(t+1,h2) =====
        #pragma unroll
        for (int m = 0; m < 4; ++m) { af03[m][0] = LDA(t, m, 0); af03[m][1] = LDA(t, m, 1); }
        #pragma unroll
        for (int n = 0; n < 2; ++n) { bf01[n][0] = LDB(t, n, 0); bf01[n][1] = LDB(t, n, 1); }
        if (t + 1 < nt) STAGE_B(t + 1, 0);
        SBAR();
        LGKM0(); SCHED_FENCE();
        __builtin_amdgcn_s_setprio(1);
        #pragma unroll
        for (int kk = 0; kk < 2; ++kk)
            #pragma unroll
            for (int m = 0; m < 4; ++m)
                #pragma unroll
                for (int n = 0; n < 2; ++n)
                    acc[m][n] = __builtin_amdgcn_mfma_f32_16x16x32_bf16(af03[m][kk], bf01[n][kk], acc[m][n], 0, 0, 0);
        __builtin_amdgcn_s_setprio(0);
        SBAR();

        // ===== q1: reads af47,bf23 | stage H(t+1,h3) =====
        #pragma unroll
        for (int m = 0; m < 4; ++m) { af47[m][0] = LDA(t, m + 4, 0); af47[m][1] = LDA(t, m + 4, 1); }
        #pragma unroll
        for (int n = 0; n < 2; ++n) { bf23[n][0] = LDB(t, n + 2, 0); bf23[n][1] = LDB(t, n + 2, 1); }
        if (t + 1 < nt) STAGE_B(t + 1, 1);
        SBAR();
        LGKM0(); SCHED_FENCE();
        __builtin_amdgcn_s_setprio(1);
        #pragma unroll
        for (int kk = 0; kk < 2; ++kk)
            #pragma unroll
            for (int m = 0; m < 4; ++m)
                #pragma unroll
                for (int n = 0; n < 2; ++n)
                    acc[m][n + 2] = __builtin_amdgcn_mfma_f32_16x16x32_bf16(af03[m][kk], bf23[n][kk], acc[m][n + 2], 0, 0, 0);
        __builtin_amdgcn_s_setprio(0);
        SBAR();

        // ===== q2: stage H(t+2,h0) =====
        if (t + 2 < nt) STAGE_A(t + 2, 0);
        SBAR();
        __builtin_amdgcn_s_setprio(1);
        #pragma unroll
        for (int kk = 0; kk < 2; ++kk)
            #pragma unroll
            for (int m = 0; m < 4; ++m)
                #pragma unroll
                for (int n = 0; n < 2; ++n)
                    acc[m + 4][n] = __builtin_amdgcn_mfma_f32_16x16x32_bf16(af47[m][kk], bf01[n][kk], acc[m + 4][n], 0, 0, 0);
        __builtin_amdgcn_s_setprio(0);
        SBAR();

        // ===== q3: stage H(t+2,h1) | vmcnt -> tile t+1 resident =====
        if (t + 2 < nt) {
            STAGE_A(t + 2, 1);
            VMCNT4();
        } else if (t + 1 < nt) {
            VMCNT0();
        }
        SBAR();
        __builtin_amdgcn_s_setprio(1);
        #pragma unroll
        for (int kk = 0; kk < 2; ++kk)
            #pragma unroll
            for (int m = 0; m < 4; ++m)
                #pragma unroll
                for (int n = 0; n < 2; ++n)
                    acc[m + 4][n + 2] = __builtin_amdgcn_mfma_f32_16x16x32_bf16(af47[m][kk], bf23[n][kk], acc[m + 4][n + 2], 0, 0, 0);
        __builtin_amdgcn_s_setprio(0);
        SBAR();
    }

    // epilogue: C/D col=lane&15, row=(lane>>4)*4+j  [m89]
    #pragma unroll
    for (int m = 0; m < 8; ++m) {
        #pragma unroll
        for (int n = 0; n < 4; ++n) {
            long gr = row0 + wr2 * 128 + m * 16 + kq * 4;
            long gc = col0 + wc2 * 64 + n * 16 + fr;
            #pragma unroll
            for (int j = 0; j < 4; ++j)
                C[(gr + j) * N + gc] = f2bf(acc[m][n][j]);
        }
    }
}

// ---------------------------------------------------------------------------
// Vsb = bf16( xb @ Bvs^T ) : M=16384, N=64, K=1024. 64x64 tile, 4 waves,
// 2-phase double-buffer. Grid = 256 blocks.
__global__ __launch_bounds__(256)
void gemm_vs(const u16* __restrict__ A, const u16* __restrict__ Bw,
             u16* __restrict__ C)
{
    __shared__ u16 lsA[2][64 * 32];
    __shared__ u16 lsB[2][64 * 32];
    const int tid  = threadIdx.x;
    const int wave = tid >> 6;
    const int lane = tid & 63;
    const long row0 = (long)blockIdx.x * 64;
    const int wr = (wave >> 1) * 32;
    const int wc = (wave & 1) * 32;
    const int fr = lane & 15;
    const int k8 = (lane >> 4) * 8;

    f32x4 acc[2][2] = {};
    const int c0 = tid;
    const u16* pa = &A [(row0 + (c0 >> 2)) * 1024 + (c0 & 3) * 8];
    const u16* pb = &Bw[((size_t)(c0 >> 2)) * 1024 + (c0 & 3) * 8];

    auto STAGE = [&](int buf, int k0) {
#ifdef HAVE_GLOAD_LDS
        gload_lds16(pa + k0, &lsA[buf][wave * 512]);
        gload_lds16(pb + k0, &lsB[buf][wave * 512]);
#else
        *(short8*)&lsA[buf][(size_t)c0 * 8] = *(const short8*)(pa + k0);
        *(short8*)&lsB[buf][(size_t)c0 * 8] = *(const short8*)(pb + k0);
#endif
    };

    STAGE(0, 0);
    __syncthreads();
    for (int t = 0; t < 32; ++t) {
        const int cur = t & 1;
        if (t + 1 < 32) STAGE(cur ^ 1, (t + 1) << 5);
        short8 af[2], bf[2];
        #pragma unroll
        for (int m = 0; m < 2; ++m)
            af[m] = *(const short8*)&lsA[cur][(wr + m * 16 + fr) * 32 + k8];
        #pragma unroll
        for (int n = 0; n < 2; ++n)
            bf[n] = *(const short8*)&lsB[cur][(wc + n * 16 + fr) * 32 + k8];
        #pragma unroll
        for (int m = 0; m < 2; ++m)
            #pragma unroll
            for (int n = 0; n < 2; ++n)
                acc[m][n] = __builtin_amdgcn_mfma_f32_16x16x32_bf16(af[m], bf[n], acc[m][n], 0, 0, 0);
        __syncthreads();
    }

    const int orow = (lane >> 4) * 4;
    #pragma unroll
    for (int m = 0; m < 2; ++m) {
        #pragma unroll
        for (int n = 0; n < 2; ++n) {
            long gr = row0 + wr + m * 16 + orow;
            int  gc = wc + n * 16 + fr;
            #pragma unroll
            for (int j = 0; j < 4; ++j)
                C[(gr + j) * 64 + gc] = f2bf(acc[m][n][j]);
        }
    }
}

// energy[site][i*16+j] = sum_d Q[site][i*64+d] * K[site][j*64+d], 1 wave/site
__global__ __launch_bounds__(256)
void energy_kernel(const u16* __restrict__ QKb, float* __restrict__ E)
{
    const int lane = threadIdx.x & 63;
    const size_t site = (size_t)blockIdx.x * 4 + (threadIdx.x >> 6);
    const u16* qrow = QKb + site * 2048;
    const int hh = lane & 15;
    const int kg = (lane >> 4) * 8;
    short8 a0 = *(const short8*)&qrow[hh * 64 + kg];
    short8 a1 = *(const short8*)&qrow[hh * 64 + 32 + kg];
    short8 b0 = *(const short8*)&qrow[1024 + hh * 64 + kg];
    short8 b1 = *(const short8*)&qrow[1024 + hh * 64 + 32 + kg];
    f32x4 acc = {};
    acc = __builtin_amdgcn_mfma_f32_16x16x32_bf16(a0, b0, acc, 0, 0, 0);
    acc = __builtin_amdgcn_mfma_f32_16x16x32_bf16(a1, b1, acc, 0, 0, 0);
    float* out = E + site * 256;
    const int ib = (lane >> 4) * 4;
    #pragma unroll
    for (int r = 0; r < 4; ++r)
        out[(ib + r) * 16 + hh] = acc[r];       // row=i, col=j
}

// ---------------------------------------------------------------------------
// single-pass chunked softmax stats over s: 256 blocks x 64-site chunks.
__global__ __launch_bounds__(256)
void stats_part(const float* __restrict__ E, float* __restrict__ pmax,
                float* __restrict__ psum)
{
    const int b = blockIdx.x, p = threadIdx.x;
    const float* e = E + (size_t)b * 64 * 256 + p;
    float m = -3.4e38f;
    float buf[64];
    #pragma unroll 8
    for (int s = 0; s < 64; ++s) {
        float v = e[(size_t)s * 256];
        buf[s] = v;
        m = fmaxf(m, v);
    }
    float z = 0.f;
    #pragma unroll 8
    for (int s = 0; s < 64; ++s) z += __expf((buf[s] - m) * 0.125f);
    pmax[b * 256 + p] = m;
    psum[b * 256 + p] = z;
}
__global__ __launch_bounds__(256)
void stats_comb(const float* __restrict__ pmax, const float* __restrict__ psum,
                float* __restrict__ gmax, float* __restrict__ invZ)
{
    const int n = blockIdx.x, p = threadIdx.x;
    float m = -3.4e38f;
    #pragma unroll 8
    for (int c = 0; c < 64; ++c) m = fmaxf(m, pmax[(n * 64 + c) * 256 + p]);
    float z = 0.f;
    #pragma unroll 8
    for (int c = 0; c < 64; ++c)
        z += psum[(n * 64 + c) * 256 + p] * __expf((pmax[(n * 64 + c) * 256 + p] - m) * 0.125f);
    gmax[n * 256 + p] = m;
    invZ[n * 256 + p] = 1.0f / z;
}

// ---------------------------------------------------------------------------
// G[srow][o] = bf16( sum_d Vsb[srow][d] * Wob[o][64*(srow&15)+d] )
__global__ __launch_bounds__(256)
void g_kernel(const u16* __restrict__ Vsb, const u16* __restrict__ Wob,
              u16* __restrict__ G)
{
    __shared__ u16 lA[64 * 64];     // [j][k granule-swizzled] 8KB
    __shared__ u16 lB[256 * 64];    // [o'][k granule-swizzled] 32KB
    const int tid = threadIdx.x;
    const int wave = tid >> 6, lane = tid & 63;
    const int op = blockIdx.x, uc = blockIdx.y, sl = blockIdx.z;

    {   // stage A: 4 threads/row, 2 granules each
        const int j = tid >> 2;
        const size_t srow = (size_t)16 * (64 * uc + j) + sl;
        #pragma unroll
        for (int h = 0; h < 2; ++h) {
            const int g = (tid & 3) + h * 4;
            u16x8 v = *(const u16x8*)&Vsb[srow * 64 + g * 8];
            *(u16x8*)&lA[j * 64 + ((g ^ (j & 7)) * 8)] = v;
        }
    }
    {   // stage B: 1 row/thread, 8 granules
        const size_t o = (size_t)op * 256 + tid;
        #pragma unroll
        for (int g = 0; g < 8; ++g) {
            u16x8 v = *(const u16x8*)&Wob[o * 1024 + 64 * sl + g * 8];
            *(u16x8*)&lB[tid * 64 + ((g ^ (tid & 7)) * 8)] = v;
        }
    }
    __syncthreads();

    const int fr = lane & 15, kq = lane >> 4;
    f32x4 acc[4][4] = {};
    #pragma unroll
    for (int kk = 0; kk < 2; ++kk) {
        short8 af[4], bq[4];
        #pragma unroll
        for (int m = 0; m < 4; ++m) {
            const int j = m * 16 + fr;
            af[m] = *(const short8*)&lA[j * 64 + (((kq + 4 * kk) ^ (j & 7)) * 8)];
        }
        #pragma unroll
        for (int n = 0; n < 4; ++n) {
            const int o = wave * 64 + n * 16 + fr;
            bq[n] = *(const short8*)&lB[o * 64 + (((kq + 4 * kk) ^ (o & 7)) * 8)];
        }
        #pragma unroll
        for (int m = 0; m < 4; ++m)
            #pragma unroll
            for (int n = 0; n < 4; ++n)
                acc[m][n] = __builtin_amdgcn_mfma_f32_16x16x32_bf16(af[m], bq[n], acc[m][n], 0, 0, 0);
    }

    // C/D: col=lane&15, row=(lane>>4)*4+j  [m89]; tile-row -> srow stride 16
    #pragma unroll
    for (int m = 0; m < 4; ++m) {
        #pragma unroll
        for (int n = 0; n < 4; ++n) {
            const int ocol = op * 256 + wave * 64 + n * 16 + fr;
            #pragma unroll
            for (int jj = 0; jj < 4; ++jj) {
                const int j = m * 16 + kq * 4 + jj;
                G[((size_t)16 * (64 * uc + j) + sl) * 1024 + ocol] = f2bf(acc[m][n][jj]);
            }
        }
    }
}

// ---------------------------------------------------------------------------
// Fused A + combine: per block (n, c):
//   a[sl][i] = sum_j exp((En[n*4096+16c+sl][i*16+j]-gmax)*0.125)*invZ
//   out[n*4096 + i*256 + c][o] = bo[o] + sum_sl a[sl][i] * G[n*4096+16c+sl][o]
__global__ __launch_bounds__(256)
void comb_kernel(const float* __restrict__ En, const float* __restrict__ gmax,
                 const float* __restrict__ invZ, const u16* __restrict__ G,
                 const float* __restrict__ bo, float* __restrict__ out)
{
    __shared__ float sm[256], sz[256], sa[256];
    const int b = blockIdx.x;
    const int n = b >> 8, c = b & 255;
    const int t = threadIdx.x;
    sm[t] = gmax[n * 256 + t];
    sz[t] = invZ[n * 256 + t];
    __syncthreads();
    {   // a-part: t = sl*16 + i
        const int sl = t >> 4, i = t & 15;
        const float* e = En + ((size_t)n * 4096 + c * 16 + sl) * 256 + i * 16;
        float a = 0.f;
        #pragma unroll
        for (int j = 0; j < 16; ++j)
            a += __expf((e[j] - sm[i * 16 + j]) * 0.125f) * sz[i * 16 + j];
        sa[sl * 16 + i] = a;
    }
    __syncthreads();

    // combine: thread owns 4 output cols o0..o0+3 across all 16 i-rows
    const int o0 = t * 4;
    const u16* gp = G + ((size_t)n * 4096 + c * 16) * 1024 + o0;
    f32x4 g[16];
    #pragma unroll
    for (int sl = 0; sl < 16; ++sl) {
        u16x4 gv = *(const u16x4*)&gp[(size_t)sl * 1024];
        g[sl][0] = bf2f(gv[0]); g[sl][1] = bf2f(gv[1]);
        g[sl][2] = bf2f(gv[2]); g[sl][3] = bf2f(gv[3]);
    }
    const f32x4 b4 = *(const f32x4*)&bo[o0];
    #pragma unroll
    for (int i = 0; i < 16; ++i) {
        f32x4 acc = b4;
        #pragma unroll
        for (int sl = 0; sl < 16; ++sl) {
            const float a = sa[sl * 16 + i];
            acc[0] += a * g[sl][0];
            acc[1] += a * g[sl][1];
            acc[2] += a * g[sl][2];
            acc[3] += a * g[sl][3];
        }
        *(f32x4*)&out[((size_t)n * 4096 + i * 256 + c) * 1024 + o0] = acc;
    }
}

// ---------------------------------------------------------------------------
extern "C" void kernel_launch(void* const* d_in, const int* in_sizes, int n_in,
                              void* d_out, int out_size, void* d_ws, size_t ws_size,
                              hipStream_t stream)
{
    const float* x  = (const float*)d_in[0];
    const float* Wq = (const float*)d_in[1];
    const float* Wk = (const float*)d_in[2];
    const float* Wv = (const float*)d_in[3];
    const float* Wo = (const float*)d_in[4];
    const float* bo = (const float*)d_in[5];
    float* out = (float*)d_out;
    char* ws = (char*)d_ws;

    u16*   xb   = (u16*)  (ws + OFF_XB);
    float* En   = (float*)(ws + OFF_EN);    // aliases xb (xb dead after gemm_vs)
    u16*   QKb  = (u16*)  (ws + OFF_QK);    // [16384][2048]: Q | K
    u16*   G    = (u16*)  (ws + OFF_QK);    // aliases QKb (dead after energy)
    u16*   Wqb  = (u16*)  (ws + OFF_WQB);   // [Wqb ; Wkb] contiguous = merged B
    u16*   Wkb  = (u16*)  (ws + OFF_WKB);
    u16*   Wob  = (u16*)  (ws + OFF_WOB);
    u16*   Bvs  = (u16*)  (ws + OFF_WVST);
    u16*   Vsb  = (u16*)  (ws + OFF_VS);
    float* gmax = (float*)(ws + OFF_GMAX);
    float* invZ = (float*)(ws + OFF_INVZ);
    float* pmax = (float*)(ws + OFF_ST);
    float* psum = (float*)(ws + OFF_ST + 262144);

    // 1. casts + head-reduced bf16 Wv
    cvt_kernel <<<9728, 256, 0, stream>>>(x, Wq, Wk, Wo, xb, Wqb, Wkb, Wob);
    wvst_kernel<<<256,  256, 0, stream>>>(Wv, Bvs);

    // 2. merged Q|K projection + head-summed V (bf16)
    gemm_qk<<<512, 512, 0, stream>>>(xb, Wqb, QKb, 16384, 2048, 1024, 3);
    gemm_vs<<<256, 256, 0, stream>>>(xb, Bvs, Vsb);

    // 3. per-site 16x16 head-Gram energy (overwrites xb region)
    energy_kernel<<<4096, 256, 0, stream>>>(QKb, En);

    // 4. softmax-over-S stats
    stats_part<<<256, 256, 0, stream>>>(En, pmax, psum);
    stats_comb<<<4,   256, 0, stream>>>(pmax, psum, gmax, invZ);

    // 5. G = Vs x Wo-slices (thin-K GEMM, bf16 out, overwrites QKb region)
    g_kernel<<<dim3(4, 16, 16), 256, 0, stream>>>(Vsb, Wob, G);

    // 6. fused A-compute + 16-term combine + bias -> fp32 d_out
    comb_kernel<<<1024, 256, 0, stream>>>(En, gmax, invZ, G, bo, out);
}

// Round 9
// 177.444 us; speedup vs baseline: 1.0570x; 1.0570x over previous
//
#include <hip/hip_runtime.h>
#include <stdint.h>

typedef unsigned short u16;
typedef unsigned int   u32;
typedef __attribute__((ext_vector_type(8))) short short8;
typedef __attribute__((ext_vector_type(4))) float f32x4;
typedef __attribute__((ext_vector_type(8))) u16   u16x8;
typedef __attribute__((ext_vector_type(4))) u16   u16x4;

// Problem constants: N=4, S=4096, E=1024, H=16, D=64
static constexpr size_t NX = (size_t)4 * 4096 * 1024;   // 16,777,216 x elems
static constexpr size_t NW = (size_t)1024 * 1024;       // 1,048,576 weight elems

// Workspace layout (bytes).
// OFF_XB: xb bf16 33.5MB, later En f32 16.8MB (xb dead after gemm_vs).
// OFF_QK: QKb bf16 67MB, later G bf16 33.5MB (QKb dead after energy).
static constexpr size_t OFF_XB   = 0;
static constexpr size_t OFF_EN   = 0;
static constexpr size_t OFF_QK   = 33554432;
static constexpr size_t OFF_WQB  = 100663296;           // 2,097,152 (Wkb contiguous after)
static constexpr size_t OFF_WKB  = 102760448;           // 2,097,152
static constexpr size_t OFF_WOB  = 104857600;           // 2,097,152
static constexpr size_t OFF_WVST = 106954752;           // 131,072  bf16 Bvs [64][1024]
static constexpr size_t OFF_VS   = 107216896;           // 2,097,152 bf16 Vsb [16384][64]
static constexpr size_t OFF_GMAX = 111411200;           // 4,096
static constexpr size_t OFF_INVZ = 111415296;           // 4,096
static constexpr size_t OFF_ST   = 111419392;           // pmax 256KB + psum 256KB

static __device__ __forceinline__ u16 f2bf(float f) {
    u32 u = __builtin_bit_cast(u32, f);
    u += 0x7fffu + ((u >> 16) & 1u);        // RNE
    return (u16)(u >> 16);
}
static __device__ __forceinline__ float bf2f(u16 v) {
    u32 u = ((u32)v) << 16;
    return __builtin_bit_cast(float, u);
}

#if __has_builtin(__builtin_amdgcn_global_load_lds)
#define HAVE_GLOAD_LDS 1
static __device__ __forceinline__ void gload_lds16(const void* g, void* l) {
    __builtin_amdgcn_global_load_lds(
        (__attribute__((address_space(1))) void*)(uintptr_t)g,
        (__attribute__((address_space(3))) void*)(uintptr_t)l,
        16, 0, 0);
}
#endif

#if __has_builtin(__builtin_amdgcn_sched_barrier)
#define SCHED_FENCE() __builtin_amdgcn_sched_barrier(0)
#else
#define SCHED_FENCE()
#endif

// ---------------------------------------------------------------------------
// fused fp32 -> bf16 conversion for x, Wq, Wk, Wo
__global__ __launch_bounds__(256)
void cvt_kernel(const float* __restrict__ x, const float* __restrict__ wq,
                const float* __restrict__ wk, const float* __restrict__ wo,
                u16* __restrict__ xb, u16* __restrict__ wqb,
                u16* __restrict__ wkb, u16* __restrict__ wob)
{
    size_t i = ((size_t)blockIdx.x * 256 + threadIdx.x) * 8;
    const float* s; u16* dst; size_t o;
    if (i < NX) { s = x; dst = xb; o = i; }
    else {
        size_t r = i - NX;
        int w = (int)(r >> 20);             // NW = 2^20
        o = r & (NW - 1);
        s   = (w == 0) ? wq  : (w == 1) ? wk  : wo;
        dst = (w == 0) ? wqb : (w == 1) ? wkb : wob;
    }
    f32x4 a = *(const f32x4*)&s[o];
    f32x4 c = *(const f32x4*)&s[o + 4];
    u16x8 v;
    v[0]=f2bf(a[0]); v[1]=f2bf(a[1]); v[2]=f2bf(a[2]); v[3]=f2bf(a[3]);
    v[4]=f2bf(c[0]); v[5]=f2bf(c[1]); v[6]=f2bf(c[2]); v[7]=f2bf(c[3]);
    *(u16x8*)&dst[o] = v;
}

// Bvs[d][e] = bf16( sum_h Wv[(h*64+d)*1024 + e] )   (B^T layout for gemm_vs)
__global__ __launch_bounds__(256)
void wvst_kernel(const float* __restrict__ Wv, u16* __restrict__ Bvs)
{
    int idx = blockIdx.x * 256 + threadIdx.x;   // 65536 total
    int d = idx >> 10;
    int e = idx & 1023;
    float s = 0.f;
    #pragma unroll
    for (int h = 0; h < 16; ++h) s += Wv[(size_t)(h * 64 + d) * 1024 + e];
    Bvs[(size_t)d * 1024 + e] = f2bf(s);
}

// ---------------------------------------------------------------------------
// 256x128-tile 8-wave bf16 GEMM, BK=32, double-buffered 48KB LDS.
// KEY CHANGE vs R4-R8: __launch_bounds__(512,4) + 48KB LDS + <=128 VGPR
// => TWO resident blocks per CU (16 waves, 4/SIMD). Simple 2-phase loop;
// cross-BLOCK skew provides the load/read/MFMA overlap that barrier-locked
// waves of a single block cannot (m114 implicit-overlap mechanism).
// Wave tile 64x64 (acc[4][4] f32x4 = 64 VGPR). Granule swizzle g^=(fr&3)
// on both stage-source and read (involution, rule #21) -> <=2-way conflicts.
__global__ __launch_bounds__(512, 4)
void gemm_qk(const u16* __restrict__ A, const u16* __restrict__ Bw,
             u16* __restrict__ C, int M, int N, int K, int lognbx)
{
    __shared__ u16 lsA[2][256 * 32];        // 2 x 16KB
    __shared__ u16 lsB[2][128 * 32];        // 2 x 8KB
    const int tid  = threadIdx.x;
    const int wave = tid >> 6;
    const int lane = tid & 63;

    // T1: XCD-bijective swizzle (gridDim.x % 8 == 0)
    const int nwg = gridDim.x;
    const int swz = ((int)blockIdx.x & 7) * (nwg >> 3) + ((int)blockIdx.x >> 3);
    const long col0 = (long)(swz & ((1 << lognbx) - 1)) * 128;
    const long row0 = (long)(swz >> lognbx) * 256;

    const int wr = (wave >> 1) * 64;        // 4 wave-rows
    const int wc = (wave & 1) * 64;         // 2 wave-cols
    const int fr = lane & 15;
    const int kq = lane >> 4;
    const int rx = fr & 3;                  // read-side swizzle

    // staging: A = 1024 granules (2/thread), B = 512 granules (1/thread)
    const int GA0 = tid, GA1 = tid + 512;
    const int rA0 = GA0 >> 2, gA0 = (GA0 & 3) ^ (rA0 & 3);
    const int rA1 = GA1 >> 2, gA1 = (GA1 & 3) ^ (rA1 & 3);
    const int rB  = tid >> 2, gB  = (tid & 3) ^ (rB & 3);
    const u16* pa0 = A  + (size_t)(row0 + rA0) * K + gA0 * 8;
    const u16* pa1 = A  + (size_t)(row0 + rA1) * K + gA1 * 8;
    const u16* pb  = Bw + (size_t)(col0 + rB ) * K + gB  * 8;

    auto STAGE = [&](int buf, int k0) {
#ifdef HAVE_GLOAD_LDS
        gload_lds16(pa0 + k0, &lsA[buf][wave * 512]);
        gload_lds16(pa1 + k0, &lsA[buf][4096 + wave * 512]);
        gload_lds16(pb  + k0, &lsB[buf][wave * 512]);
#else
        *(short8*)&lsA[buf][(size_t)GA0 * 8] = *(const short8*)(pa0 + k0);
        *(short8*)&lsA[buf][(size_t)GA1 * 8] = *(const short8*)(pa1 + k0);
        *(short8*)&lsB[buf][(size_t)tid * 8] = *(const short8*)(pb  + k0);
#endif
    };

    f32x4 acc[4][4] = {};

    STAGE(0, 0);
    __syncthreads();

    const int nt = K >> 5;
    for (int t = 0; t < nt; ++t) {
        const int cur = t & 1;
        if (t + 1 < nt) STAGE(cur ^ 1, (t + 1) << 5);

        short8 af[4], bf[4];
        #pragma unroll
        for (int m = 0; m < 4; ++m)
            af[m] = *(const short8*)&lsA[cur][(wr + m * 16 + fr) * 32 + ((kq ^ rx) * 8)];
        #pragma unroll
        for (int n = 0; n < 4; ++n)
            bf[n] = *(const short8*)&lsB[cur][(wc + n * 16 + fr) * 32 + ((kq ^ rx) * 8)];
        SCHED_FENCE();

        __builtin_amdgcn_s_setprio(1);
        #pragma unroll
        for (int m = 0; m < 4; ++m)
            #pragma unroll
            for (int n = 0; n < 4; ++n)
                acc[m][n] = __builtin_amdgcn_mfma_f32_16x16x32_bf16(af[m], bf[n], acc[m][n], 0, 0, 0);
        __builtin_amdgcn_s_setprio(0);

        __syncthreads();
    }

    // epilogue: C/D col=lane&15, row=(lane>>4)*4+j  [m89]
    #pragma unroll
    for (int m = 0; m < 4; ++m) {
        #pragma unroll
        for (int n = 0; n < 4; ++n) {
            long gr = row0 + wr + m * 16 + kq * 4;
            long gc = col0 + wc + n * 16 + fr;
            #pragma unroll
            for (int j = 0; j < 4; ++j)
                C[(gr + j) * N + gc] = f2bf(acc[m][n][j]);
        }
    }
}

// ---------------------------------------------------------------------------
// Vsb = bf16( xb @ Bvs^T ) : M=16384, N=64, K=1024. 64x64 tile, 4 waves,
// 2-phase double-buffer. Grid = 256 blocks.
__global__ __launch_bounds__(256)
void gemm_vs(const u16* __restrict__ A, const u16* __restrict__ Bw,
             u16* __restrict__ C)
{
    __shared__ u16 lsA[2][64 * 32];
    __shared__ u16 lsB[2][64 * 32];
    const int tid  = threadIdx.x;
    const int wave = tid >> 6;
    const int lane = tid & 63;
    const long row0 = (long)blockIdx.x * 64;
    const int wr = (wave >> 1) * 32;
    const int wc = (wave & 1) * 32;
    const int fr = lane & 15;
    const int k8 = (lane >> 4) * 8;

    f32x4 acc[2][2] = {};
    const int c0 = tid;
    const u16* pa = &A [(row0 + (c0 >> 2)) * 1024 + (c0 & 3) * 8];
    const u16* pb = &Bw[((size_t)(c0 >> 2)) * 1024 + (c0 & 3) * 8];

    auto STAGE = [&](int buf, int k0) {
#ifdef HAVE_GLOAD_LDS
        gload_lds16(pa + k0, &lsA[buf][wave * 512]);
        gload_lds16(pb + k0, &lsB[buf][wave * 512]);
#else
        *(short8*)&lsA[buf][(size_t)c0 * 8] = *(const short8*)(pa + k0);
        *(short8*)&lsB[buf][(size_t)c0 * 8] = *(const short8*)(pb + k0);
#endif
    };

    STAGE(0, 0);
    __syncthreads();
    for (int t = 0; t < 32; ++t) {
        const int cur = t & 1;
        if (t + 1 < 32) STAGE(cur ^ 1, (t + 1) << 5);
        short8 af[2], bf[2];
        #pragma unroll
        for (int m = 0; m < 2; ++m)
            af[m] = *(const short8*)&lsA[cur][(wr + m * 16 + fr) * 32 + k8];
        #pragma unroll
        for (int n = 0; n < 2; ++n)
            bf[n] = *(const short8*)&lsB[cur][(wc + n * 16 + fr) * 32 + k8];
        #pragma unroll
        for (int m = 0; m < 2; ++m)
            #pragma unroll
            for (int n = 0; n < 2; ++n)
                acc[m][n] = __builtin_amdgcn_mfma_f32_16x16x32_bf16(af[m], bf[n], acc[m][n], 0, 0, 0);
        __syncthreads();
    }

    const int orow = (lane >> 4) * 4;
    #pragma unroll
    for (int m = 0; m < 2; ++m) {
        #pragma unroll
        for (int n = 0; n < 2; ++n) {
            long gr = row0 + wr + m * 16 + orow;
            int  gc = wc + n * 16 + fr;
            #pragma unroll
            for (int j = 0; j < 4; ++j)
                C[(gr + j) * 64 + gc] = f2bf(acc[m][n][j]);
        }
    }
}

// energy[site][i*16+j] = sum_d Q[site][i*64+d] * K[site][j*64+d], 1 wave/site
__global__ __launch_bounds__(256)
void energy_kernel(const u16* __restrict__ QKb, float* __restrict__ E)
{
    const int lane = threadIdx.x & 63;
    const size_t site = (size_t)blockIdx.x * 4 + (threadIdx.x >> 6);
    const u16* qrow = QKb + site * 2048;
    const int hh = lane & 15;
    const int kg = (lane >> 4) * 8;
    short8 a0 = *(const short8*)&qrow[hh * 64 + kg];
    short8 a1 = *(const short8*)&qrow[hh * 64 + 32 + kg];
    short8 b0 = *(const short8*)&qrow[1024 + hh * 64 + kg];
    short8 b1 = *(const short8*)&qrow[1024 + hh * 64 + 32 + kg];
    f32x4 acc = {};
    acc = __builtin_amdgcn_mfma_f32_16x16x32_bf16(a0, b0, acc, 0, 0, 0);
    acc = __builtin_amdgcn_mfma_f32_16x16x32_bf16(a1, b1, acc, 0, 0, 0);
    float* out = E + site * 256;
    const int ib = (lane >> 4) * 4;
    #pragma unroll
    for (int r = 0; r < 4; ++r)
        out[(ib + r) * 16 + hh] = acc[r];       // row=i, col=j
}

// ---------------------------------------------------------------------------
// single-pass ONLINE softmax stats over s: 256 blocks x 64-site chunks.
// Online max+rescale accumulation (no per-thread array -> no scratch; the
// old buf[64] version allocated in scratch: VGPR_Count=8, 16.9MB writes).
__global__ __launch_bounds__(256)
void stats_part(const float* __restrict__ E, float* __restrict__ pmax,
                float* __restrict__ psum)
{
    const int b = blockIdx.x, p = threadIdx.x;
    const float* e = E + (size_t)b * 64 * 256 + p;
    float m = -3.4e38f, z = 0.f;
    for (int s = 0; s < 64; ++s) {
        float v = e[(size_t)s * 256];
        float mn = fmaxf(m, v);
        z = z * __expf((m - mn) * 0.125f) + __expf((v - mn) * 0.125f);
        m = mn;
    }
    pmax[b * 256 + p] = m;
    psum[b * 256 + p] = z;
}
__global__ __launch_bounds__(256)
void stats_comb(const float* __restrict__ pmax, const float* __restrict__ psum,
                float* __restrict__ gmax, float* __restrict__ invZ)
{
    const int n = blockIdx.x, p = threadIdx.x;
    float m = -3.4e38f;
    for (int c = 0; c < 64; ++c) m = fmaxf(m, pmax[(n * 64 + c) * 256 + p]);
    float z = 0.f;
    for (int c = 0; c < 64; ++c)
        z += psum[(n * 64 + c) * 256 + p] * __expf((pmax[(n * 64 + c) * 256 + p] - m) * 0.125f);
    gmax[n * 256 + p] = m;
    invZ[n * 256 + p] = 1.0f / z;
}

// ---------------------------------------------------------------------------
// G[srow][o] = bf16( sum_d Vsb[srow][d] * Wob[o][64*(srow&15)+d] )
__global__ __launch_bounds__(256)
void g_kernel(const u16* __restrict__ Vsb, const u16* __restrict__ Wob,
              u16* __restrict__ G)
{
    __shared__ u16 lA[64 * 64];     // [j][k granule-swizzled] 8KB
    __shared__ u16 lB[256 * 64];    // [o'][k granule-swizzled] 32KB
    const int tid = threadIdx.x;
    const int wave = tid >> 6, lane = tid & 63;
    const int op = blockIdx.x, uc = blockIdx.y, sl = blockIdx.z;

    {   // stage A: 4 threads/row, 2 granules each
        const int j = tid >> 2;
        const size_t srow = (size_t)16 * (64 * uc + j) + sl;
        #pragma unroll
        for (int h = 0; h < 2; ++h) {
            const int g = (tid & 3) + h * 4;
            u16x8 v = *(const u16x8*)&Vsb[srow * 64 + g * 8];
            *(u16x8*)&lA[j * 64 + ((g ^ (j & 7)) * 8)] = v;
        }
    }
    {   // stage B: 1 row/thread, 8 granules
        const size_t o = (size_t)op * 256 + tid;
        #pragma unroll
        for (int g = 0; g < 8; ++g) {
            u16x8 v = *(const u16x8*)&Wob[o * 1024 + 64 * sl + g * 8];
            *(u16x8*)&lB[tid * 64 + ((g ^ (tid & 7)) * 8)] = v;
        }
    }
    __syncthreads();

    const int fr = lane & 15, kq = lane >> 4;
    f32x4 acc[4][4] = {};
    #pragma unroll
    for (int kk = 0; kk < 2; ++kk) {
        short8 af[4], bq[4];
        #pragma unroll
        for (int m = 0; m < 4; ++m) {
            const int j = m * 16 + fr;
            af[m] = *(const short8*)&lA[j * 64 + (((kq + 4 * kk) ^ (j & 7)) * 8)];
        }
        #pragma unroll
        for (int n = 0; n < 4; ++n) {
            const int o = wave * 64 + n * 16 + fr;
            bq[n] = *(const short8*)&lB[o * 64 + (((kq + 4 * kk) ^ (o & 7)) * 8)];
        }
        #pragma unroll
        for (int m = 0; m < 4; ++m)
            #pragma unroll
            for (int n = 0; n < 4; ++n)
                acc[m][n] = __builtin_amdgcn_mfma_f32_16x16x32_bf16(af[m], bq[n], acc[m][n], 0, 0, 0);
    }

    // C/D: col=lane&15, row=(lane>>4)*4+j  [m89]; tile-row -> srow stride 16
    #pragma unroll
    for (int m = 0; m < 4; ++m) {
        #pragma unroll
        for (int n = 0; n < 4; ++n) {
            const int ocol = op * 256 + wave * 64 + n * 16 + fr;
            #pragma unroll
            for (int jj = 0; jj < 4; ++jj) {
                const int j = m * 16 + kq * 4 + jj;
                G[((size_t)16 * (64 * uc + j) + sl) * 1024 + ocol] = f2bf(acc[m][n][jj]);
            }
        }
    }
}

// ---------------------------------------------------------------------------
// Fused A + combine: per block (n, c):
//   a[sl][i] = sum_j exp((En[n*4096+16c+sl][i*16+j]-gmax)*0.125)*invZ
//   out[n*4096 + i*256 + c][o] = bo[o] + sum_sl a[sl][i] * G[n*4096+16c+sl][o]
__global__ __launch_bounds__(256)
void comb_kernel(const float* __restrict__ En, const float* __restrict__ gmax,
                 const float* __restrict__ invZ, const u16* __restrict__ G,
                 const float* __restrict__ bo, float* __restrict__ out)
{
    __shared__ float sm[256], sz[256], sa[256];
    const int b = blockIdx.x;
    const int n = b >> 8, c = b & 255;
    const int t = threadIdx.x;
    sm[t] = gmax[n * 256 + t];
    sz[t] = invZ[n * 256 + t];
    __syncthreads();
    {   // a-part: t = sl*16 + i
        const int sl = t >> 4, i = t & 15;
        const float* e = En + ((size_t)n * 4096 + c * 16 + sl) * 256 + i * 16;
        float a = 0.f;
        #pragma unroll
        for (int j = 0; j < 16; ++j)
            a += __expf((e[j] - sm[i * 16 + j]) * 0.125f) * sz[i * 16 + j];
        sa[sl * 16 + i] = a;
    }
    __syncthreads();

    // combine: thread owns 4 output cols o0..o0+3 across all 16 i-rows
    const int o0 = t * 4;
    const u16* gp = G + ((size_t)n * 4096 + c * 16) * 1024 + o0;
    f32x4 g[16];
    #pragma unroll
    for (int sl = 0; sl < 16; ++sl) {
        u16x4 gv = *(const u16x4*)&gp[(size_t)sl * 1024];
        g[sl][0] = bf2f(gv[0]); g[sl][1] = bf2f(gv[1]);
        g[sl][2] = bf2f(gv[2]); g[sl][3] = bf2f(gv[3]);
    }
    const f32x4 b4 = *(const f32x4*)&bo[o0];
    #pragma unroll
    for (int i = 0; i < 16; ++i) {
        f32x4 acc = b4;
        #pragma unroll
        for (int sl = 0; sl < 16; ++sl) {
            const float a = sa[sl * 16 + i];
            acc[0] += a * g[sl][0];
            acc[1] += a * g[sl][1];
            acc[2] += a * g[sl][2];
            acc[3] += a * g[sl][3];
        }
        *(f32x4*)&out[((size_t)n * 4096 + i * 256 + c) * 1024 + o0] = acc;
    }
}

// ---------------------------------------------------------------------------
extern "C" void kernel_launch(void* const* d_in, const int* in_sizes, int n_in,
                              void* d_out, int out_size, void* d_ws, size_t ws_size,
                              hipStream_t stream)
{
    const float* x  = (const float*)d_in[0];
    const float* Wq = (const float*)d_in[1];
    const float* Wk = (const float*)d_in[2];
    const float* Wv = (const float*)d_in[3];
    const float* Wo = (const float*)d_in[4];
    const float* bo = (const float*)d_in[5];
    float* out = (float*)d_out;
    char* ws = (char*)d_ws;

    u16*   xb   = (u16*)  (ws + OFF_XB);
    float* En   = (float*)(ws + OFF_EN);    // aliases xb (xb dead after gemm_vs)
    u16*   QKb  = (u16*)  (ws + OFF_QK);    // [16384][2048]: Q | K
    u16*   G    = (u16*)  (ws + OFF_QK);    // aliases QKb (dead after energy)
    u16*   Wqb  = (u16*)  (ws + OFF_WQB);   // [Wqb ; Wkb] contiguous = merged B
    u16*   Wkb  = (u16*)  (ws + OFF_WKB);
    u16*   Wob  = (u16*)  (ws + OFF_WOB);
    u16*   Bvs  = (u16*)  (ws + OFF_WVST);
    u16*   Vsb  = (u16*)  (ws + OFF_VS);
    float* gmax = (float*)(ws + OFF_GMAX);
    float* invZ = (float*)(ws + OFF_INVZ);
    float* pmax = (float*)(ws + OFF_ST);
    float* psum = (float*)(ws + OFF_ST + 262144);

    // 1. casts + head-reduced bf16 Wv
    cvt_kernel <<<9728, 256, 0, stream>>>(x, Wq, Wk, Wo, xb, Wqb, Wkb, Wob);
    wvst_kernel<<<256,  256, 0, stream>>>(Wv, Bvs);

    // 2. merged Q|K projection (256x128 tiles, 64x16=1024 blocks, 2/CU) + Vs
    gemm_qk<<<1024, 512, 0, stream>>>(xb, Wqb, QKb, 16384, 2048, 1024, 4);
    gemm_vs<<<256, 256, 0, stream>>>(xb, Bvs, Vsb);

    // 3. per-site 16x16 head-Gram energy (overwrites xb region)
    energy_kernel<<<4096, 256, 0, stream>>>(QKb, En);

    // 4. softmax-over-S stats (online, scratch-free)
    stats_part<<<256, 256, 0, stream>>>(En, pmax, psum);
    stats_comb<<<4,   256, 0, stream>>>(pmax, psum, gmax, invZ);

    // 5. G = Vs x Wo-slices (thin-K GEMM, bf16 out, overwrites QKb region)
    g_kernel<<<dim3(4, 16, 16), 256, 0, stream>>>(Vsb, Wob, G);

    // 6. fused A-compute + 16-term combine + bias -> fp32 d_out
    comb_kernel<<<1024, 256, 0, stream>>>(En, gmax, invZ, G, bo, out);
}

// Round 10
// 176.253 us; speedup vs baseline: 1.0641x; 1.0068x over previous
//
#include <hip/hip_runtime.h>
#include <stdint.h>

typedef unsigned short u16;
typedef unsigned int   u32;
typedef __attribute__((ext_vector_type(8))) short short8;
typedef __attribute__((ext_vector_type(4))) float f32x4;
typedef __attribute__((ext_vector_type(8))) u16   u16x8;
typedef __attribute__((ext_vector_type(4))) u16   u16x4;

// Problem constants: N=4, S=4096, E=1024, H=16, D=64
static constexpr size_t NX = (size_t)4 * 4096 * 1024;   // 16,777,216 x elems
static constexpr size_t NW = (size_t)1024 * 1024;       // 1,048,576 weight elems

// Workspace layout (bytes).
// OFF_XB: xb bf16 33.5MB, later En f32 16.8MB (xb dead after gemm_vs).
// OFF_QK: QKb bf16 67MB, later G bf16 33.5MB (QKb dead after energy).
static constexpr size_t OFF_XB   = 0;
static constexpr size_t OFF_EN   = 0;
static constexpr size_t OFF_QK   = 33554432;
static constexpr size_t OFF_WQB  = 100663296;           // 2,097,152 (Wkb contiguous after)
static constexpr size_t OFF_WKB  = 102760448;           // 2,097,152
static constexpr size_t OFF_WOB  = 104857600;           // 2,097,152
static constexpr size_t OFF_WVST = 106954752;           // 131,072  bf16 Bvs [64][1024]
static constexpr size_t OFF_VS   = 107216896;           // 2,097,152 bf16 Vsb [16384][64]
static constexpr size_t OFF_GMAX = 111411200;           // 4,096
static constexpr size_t OFF_INVZ = 111415296;           // 4,096
static constexpr size_t OFF_ST   = 111419392;           // pmax 256KB + psum 256KB

static __device__ __forceinline__ u16 f2bf(float f) {
    u32 u = __builtin_bit_cast(u32, f);
    u += 0x7fffu + ((u >> 16) & 1u);        // RNE
    return (u16)(u >> 16);
}
static __device__ __forceinline__ float bf2f(u16 v) {
    u32 u = ((u32)v) << 16;
    return __builtin_bit_cast(float, u);
}

#if __has_builtin(__builtin_amdgcn_global_load_lds)
#define HAVE_GLOAD_LDS 1
static __device__ __forceinline__ void gload_lds16(const void* g, void* l) {
    __builtin_amdgcn_global_load_lds(
        (__attribute__((address_space(1))) void*)(uintptr_t)g,
        (__attribute__((address_space(3))) void*)(uintptr_t)l,
        16, 0, 0);
}
#endif

#if __has_builtin(__builtin_amdgcn_sched_barrier)
#define SCHED_FENCE() __builtin_amdgcn_sched_barrier(0)
#else
#define SCHED_FENCE()
#endif

// ---------------------------------------------------------------------------
// fused fp32 -> bf16 conversion for x, Wq, Wk, Wo
__global__ __launch_bounds__(256)
void cvt_kernel(const float* __restrict__ x, const float* __restrict__ wq,
                const float* __restrict__ wk, const float* __restrict__ wo,
                u16* __restrict__ xb, u16* __restrict__ wqb,
                u16* __restrict__ wkb, u16* __restrict__ wob)
{
    size_t i = ((size_t)blockIdx.x * 256 + threadIdx.x) * 8;
    const float* s; u16* dst; size_t o;
    if (i < NX) { s = x; dst = xb; o = i; }
    else {
        size_t r = i - NX;
        int w = (int)(r >> 20);             // NW = 2^20
        o = r & (NW - 1);
        s   = (w == 0) ? wq  : (w == 1) ? wk  : wo;
        dst = (w == 0) ? wqb : (w == 1) ? wkb : wob;
    }
    f32x4 a = *(const f32x4*)&s[o];
    f32x4 c = *(const f32x4*)&s[o + 4];
    u16x8 v;
    v[0]=f2bf(a[0]); v[1]=f2bf(a[1]); v[2]=f2bf(a[2]); v[3]=f2bf(a[3]);
    v[4]=f2bf(c[0]); v[5]=f2bf(c[1]); v[6]=f2bf(c[2]); v[7]=f2bf(c[3]);
    *(u16x8*)&dst[o] = v;
}

// Bvs[d][e] = bf16( sum_h Wv[(h*64+d)*1024 + e] )   (B^T layout for gemm_vs)
__global__ __launch_bounds__(256)
void wvst_kernel(const float* __restrict__ Wv, u16* __restrict__ Bvs)
{
    int idx = blockIdx.x * 256 + threadIdx.x;   // 65536 total
    int d = idx >> 10;
    int e = idx & 1023;
    float s = 0.f;
    #pragma unroll
    for (int h = 0; h < 16; ++h) s += Wv[(size_t)(h * 64 + d) * 1024 + e];
    Bvs[(size_t)d * 1024 + e] = f2bf(s);
}

// ---------------------------------------------------------------------------
// 256x128-tile 8-wave bf16 GEMM, BK=32, double-buffered 48KB LDS, 2+ blocks/CU.
// SWIZZLE FIX vs R9: BK=32 rows are 64B (16 banks), so rows alias every TWO
// rows (128B wrap). Swizzle must key on (row>>1)&3, not row&3 (R9's fr&3 gave
// 8.4M bank conflicts; R3's (fr>>1)&3 measured 0 at the same BK). Involution:
// stage fetches source granule (G&3)^((row>>1)&3) into linear LDS slot; read
// of logical granule kq accesses kq^((fr>>1)&3). Bank check: 2 lanes/bank
// (fr vs fr+8) = free wave64 minimum [m136].
__global__ __launch_bounds__(512, 4)
void gemm_qk(const u16* __restrict__ A, const u16* __restrict__ Bw,
             u16* __restrict__ C, int M, int N, int K, int lognbx)
{
    __shared__ u16 lsA[2][256 * 32];        // 2 x 16KB
    __shared__ u16 lsB[2][128 * 32];        // 2 x 8KB
    const int tid  = threadIdx.x;
    const int wave = tid >> 6;
    const int lane = tid & 63;

    // T1: XCD-bijective swizzle (gridDim.x % 8 == 0)
    const int nwg = gridDim.x;
    const int swz = ((int)blockIdx.x & 7) * (nwg >> 3) + ((int)blockIdx.x >> 3);
    const long col0 = (long)(swz & ((1 << lognbx) - 1)) * 128;
    const long row0 = (long)(swz >> lognbx) * 256;

    const int wr = (wave >> 1) * 64;        // 4 wave-rows
    const int wc = (wave & 1) * 64;         // 2 wave-cols
    const int fr = lane & 15;
    const int kq = lane >> 4;
    const int rx = (fr >> 1) & 3;           // read-side swizzle (row-pair keyed)

    // staging: A = 1024 granules (2/thread), B = 512 granules (1/thread)
    const int GA0 = tid, GA1 = tid + 512;
    const int rA0 = GA0 >> 2, gA0 = (GA0 & 3) ^ ((rA0 >> 1) & 3);
    const int rA1 = GA1 >> 2, gA1 = (GA1 & 3) ^ ((rA1 >> 1) & 3);
    const int rB  = tid >> 2, gB  = (tid & 3) ^ ((rB >> 1) & 3);
    const u16* pa0 = A  + (size_t)(row0 + rA0) * K + gA0 * 8;
    const u16* pa1 = A  + (size_t)(row0 + rA1) * K + gA1 * 8;
    const u16* pb  = Bw + (size_t)(col0 + rB ) * K + gB  * 8;

    auto STAGE = [&](int buf, int k0) {
#ifdef HAVE_GLOAD_LDS
        gload_lds16(pa0 + k0, &lsA[buf][wave * 512]);
        gload_lds16(pa1 + k0, &lsA[buf][4096 + wave * 512]);
        gload_lds16(pb  + k0, &lsB[buf][wave * 512]);
#else
        *(short8*)&lsA[buf][(size_t)GA0 * 8] = *(const short8*)(pa0 + k0);
        *(short8*)&lsA[buf][(size_t)GA1 * 8] = *(const short8*)(pa1 + k0);
        *(short8*)&lsB[buf][(size_t)tid * 8] = *(const short8*)(pb  + k0);
#endif
    };

    f32x4 acc[4][4] = {};

    STAGE(0, 0);
    __syncthreads();

    const int nt = K >> 5;
    for (int t = 0; t < nt; ++t) {
        const int cur = t & 1;
        if (t + 1 < nt) STAGE(cur ^ 1, (t + 1) << 5);

        short8 af[4], bf[4];
        #pragma unroll
        for (int m = 0; m < 4; ++m)
            af[m] = *(const short8*)&lsA[cur][(wr + m * 16 + fr) * 32 + ((kq ^ rx) * 8)];
        #pragma unroll
        for (int n = 0; n < 4; ++n)
            bf[n] = *(const short8*)&lsB[cur][(wc + n * 16 + fr) * 32 + ((kq ^ rx) * 8)];
        SCHED_FENCE();

        __builtin_amdgcn_s_setprio(1);
        #pragma unroll
        for (int m = 0; m < 4; ++m)
            #pragma unroll
            for (int n = 0; n < 4; ++n)
                acc[m][n] = __builtin_amdgcn_mfma_f32_16x16x32_bf16(af[m], bf[n], acc[m][n], 0, 0, 0);
        __builtin_amdgcn_s_setprio(0);

        __syncthreads();
    }

    // epilogue: C/D col=lane&15, row=(lane>>4)*4+j  [m89]
    #pragma unroll
    for (int m = 0; m < 4; ++m) {
        #pragma unroll
        for (int n = 0; n < 4; ++n) {
            long gr = row0 + wr + m * 16 + kq * 4;
            long gc = col0 + wc + n * 16 + fr;
            #pragma unroll
            for (int j = 0; j < 4; ++j)
                C[(gr + j) * N + gc] = f2bf(acc[m][n][j]);
        }
    }
}

// ---------------------------------------------------------------------------
// Vsb = bf16( xb @ Bvs^T ) : M=16384, N=64, K=1024. 64x64 tile, 4 waves,
// 2-phase double-buffer. Grid = 256 blocks.
__global__ __launch_bounds__(256)
void gemm_vs(const u16* __restrict__ A, const u16* __restrict__ Bw,
             u16* __restrict__ C)
{
    __shared__ u16 lsA[2][64 * 32];
    __shared__ u16 lsB[2][64 * 32];
    const int tid  = threadIdx.x;
    const int wave = tid >> 6;
    const int lane = tid & 63;
    const long row0 = (long)blockIdx.x * 64;
    const int wr = (wave >> 1) * 32;
    const int wc = (wave & 1) * 32;
    const int fr = lane & 15;
    const int k8 = (lane >> 4) * 8;

    f32x4 acc[2][2] = {};
    const int c0 = tid;
    const u16* pa = &A [(row0 + (c0 >> 2)) * 1024 + (c0 & 3) * 8];
    const u16* pb = &Bw[((size_t)(c0 >> 2)) * 1024 + (c0 & 3) * 8];

    auto STAGE = [&](int buf, int k0) {
#ifdef HAVE_GLOAD_LDS
        gload_lds16(pa + k0, &lsA[buf][wave * 512]);
        gload_lds16(pb + k0, &lsB[buf][wave * 512]);
#else
        *(short8*)&lsA[buf][(size_t)c0 * 8] = *(const short8*)(pa + k0);
        *(short8*)&lsB[buf][(size_t)c0 * 8] = *(const short8*)(pb + k0);
#endif
    };

    STAGE(0, 0);
    __syncthreads();
    for (int t = 0; t < 32; ++t) {
        const int cur = t & 1;
        if (t + 1 < 32) STAGE(cur ^ 1, (t + 1) << 5);
        short8 af[2], bf[2];
        #pragma unroll
        for (int m = 0; m < 2; ++m)
            af[m] = *(const short8*)&lsA[cur][(wr + m * 16 + fr) * 32 + k8];
        #pragma unroll
        for (int n = 0; n < 2; ++n)
            bf[n] = *(const short8*)&lsB[cur][(wc + n * 16 + fr) * 32 + k8];
        #pragma unroll
        for (int m = 0; m < 2; ++m)
            #pragma unroll
            for (int n = 0; n < 2; ++n)
                acc[m][n] = __builtin_amdgcn_mfma_f32_16x16x32_bf16(af[m], bf[n], acc[m][n], 0, 0, 0);
        __syncthreads();
    }

    const int orow = (lane >> 4) * 4;
    #pragma unroll
    for (int m = 0; m < 2; ++m) {
        #pragma unroll
        for (int n = 0; n < 2; ++n) {
            long gr = row0 + wr + m * 16 + orow;
            int  gc = wc + n * 16 + fr;
            #pragma unroll
            for (int j = 0; j < 4; ++j)
                C[(gr + j) * 64 + gc] = f2bf(acc[m][n][j]);
        }
    }
}

// energy[site][i*16+j] = sum_d Q[site][i*64+d] * K[site][j*64+d], 1 wave/site
__global__ __launch_bounds__(256)
void energy_kernel(const u16* __restrict__ QKb, float* __restrict__ E)
{
    const int lane = threadIdx.x & 63;
    const size_t site = (size_t)blockIdx.x * 4 + (threadIdx.x >> 6);
    const u16* qrow = QKb + site * 2048;
    const int hh = lane & 15;
    const int kg = (lane >> 4) * 8;
    short8 a0 = *(const short8*)&qrow[hh * 64 + kg];
    short8 a1 = *(const short8*)&qrow[hh * 64 + 32 + kg];
    short8 b0 = *(const short8*)&qrow[1024 + hh * 64 + kg];
    short8 b1 = *(const short8*)&qrow[1024 + hh * 64 + 32 + kg];
    f32x4 acc = {};
    acc = __builtin_amdgcn_mfma_f32_16x16x32_bf16(a0, b0, acc, 0, 0, 0);
    acc = __builtin_amdgcn_mfma_f32_16x16x32_bf16(a1, b1, acc, 0, 0, 0);
    float* out = E + site * 256;
    const int ib = (lane >> 4) * 4;
    #pragma unroll
    for (int r = 0; r < 4; ++r)
        out[(ib + r) * 16 + hh] = acc[r];       // row=i, col=j
}

// ---------------------------------------------------------------------------
// single-pass ONLINE softmax stats over s: 256 blocks x 64-site chunks.
__global__ __launch_bounds__(256)
void stats_part(const float* __restrict__ E, float* __restrict__ pmax,
                float* __restrict__ psum)
{
    const int b = blockIdx.x, p = threadIdx.x;
    const float* e = E + (size_t)b * 64 * 256 + p;
    float m = -3.4e38f, z = 0.f;
    for (int s = 0; s < 64; ++s) {
        float v = e[(size_t)s * 256];
        float mn = fmaxf(m, v);
        z = z * __expf((m - mn) * 0.125f) + __expf((v - mn) * 0.125f);
        m = mn;
    }
    pmax[b * 256 + p] = m;
    psum[b * 256 + p] = z;
}
__global__ __launch_bounds__(256)
void stats_comb(const float* __restrict__ pmax, const float* __restrict__ psum,
                float* __restrict__ gmax, float* __restrict__ invZ)
{
    const int n = blockIdx.x, p = threadIdx.x;
    float m = -3.4e38f;
    for (int c = 0; c < 64; ++c) m = fmaxf(m, pmax[(n * 64 + c) * 256 + p]);
    float z = 0.f;
    for (int c = 0; c < 64; ++c)
        z += psum[(n * 64 + c) * 256 + p] * __expf((pmax[(n * 64 + c) * 256 + p] - m) * 0.125f);
    gmax[n * 256 + p] = m;
    invZ[n * 256 + p] = 1.0f / z;
}

// ---------------------------------------------------------------------------
// G[srow][o] = bf16( sum_d Vsb[srow][d] * Wob[o][64*(srow&15)+d] )
__global__ __launch_bounds__(256)
void g_kernel(const u16* __restrict__ Vsb, const u16* __restrict__ Wob,
              u16* __restrict__ G)
{
    __shared__ u16 lA[64 * 64];     // [j][k granule-swizzled] 8KB
    __shared__ u16 lB[256 * 64];    // [o'][k granule-swizzled] 32KB
    const int tid = threadIdx.x;
    const int wave = tid >> 6, lane = tid & 63;
    const int op = blockIdx.x, uc = blockIdx.y, sl = blockIdx.z;

    {   // stage A: 4 threads/row, 2 granules each
        const int j = tid >> 2;
        const size_t srow = (size_t)16 * (64 * uc + j) + sl;
        #pragma unroll
        for (int h = 0; h < 2; ++h) {
            const int g = (tid & 3) + h * 4;
            u16x8 v = *(const u16x8*)&Vsb[srow * 64 + g * 8];
            *(u16x8*)&lA[j * 64 + ((g ^ (j & 7)) * 8)] = v;
        }
    }
    {   // stage B: 1 row/thread, 8 granules
        const size_t o = (size_t)op * 256 + tid;
        #pragma unroll
        for (int g = 0; g < 8; ++g) {
            u16x8 v = *(const u16x8*)&Wob[o * 1024 + 64 * sl + g * 8];
            *(u16x8*)&lB[tid * 64 + ((g ^ (tid & 7)) * 8)] = v;
        }
    }
    __syncthreads();

    const int fr = lane & 15, kq = lane >> 4;
    f32x4 acc[4][4] = {};
    #pragma unroll
    for (int kk = 0; kk < 2; ++kk) {
        short8 af[4], bq[4];
        #pragma unroll
        for (int m = 0; m < 4; ++m) {
            const int j = m * 16 + fr;
            af[m] = *(const short8*)&lA[j * 64 + (((kq + 4 * kk) ^ (j & 7)) * 8)];
        }
        #pragma unroll
        for (int n = 0; n < 4; ++n) {
            const int o = wave * 64 + n * 16 + fr;
            bq[n] = *(const short8*)&lB[o * 64 + (((kq + 4 * kk) ^ (o & 7)) * 8)];
        }
        #pragma unroll
        for (int m = 0; m < 4; ++m)
            #pragma unroll
            for (int n = 0; n < 4; ++n)
                acc[m][n] = __builtin_amdgcn_mfma_f32_16x16x32_bf16(af[m], bq[n], acc[m][n], 0, 0, 0);
    }

    // C/D: col=lane&15, row=(lane>>4)*4+j  [m89]; tile-row -> srow stride 16
    #pragma unroll
    for (int m = 0; m < 4; ++m) {
        #pragma unroll
        for (int n = 0; n < 4; ++n) {
            const int ocol = op * 256 + wave * 64 + n * 16 + fr;
            #pragma unroll
            for (int jj = 0; jj < 4; ++jj) {
                const int j = m * 16 + kq * 4 + jj;
                G[((size_t)16 * (64 * uc + j) + sl) * 1024 + ocol] = f2bf(acc[m][n][jj]);
            }
        }
    }
}

// ---------------------------------------------------------------------------
// Fused A + combine: per block (n, c):
//   a[sl][i] = sum_j exp((En[n*4096+16c+sl][i*16+j]-gmax)*0.125)*invZ
//   out[n*4096 + i*256 + c][o] = bo[o] + sum_sl a[sl][i] * G[n*4096+16c+sl][o]
__global__ __launch_bounds__(256)
void comb_kernel(const float* __restrict__ En, const float* __restrict__ gmax,
                 const float* __restrict__ invZ, const u16* __restrict__ G,
                 const float* __restrict__ bo, float* __restrict__ out)
{
    __shared__ float sm[256], sz[256], sa[256];
    const int b = blockIdx.x;
    const int n = b >> 8, c = b & 255;
    const int t = threadIdx.x;
    sm[t] = gmax[n * 256 + t];
    sz[t] = invZ[n * 256 + t];
    __syncthreads();
    {   // a-part: t = sl*16 + i
        const int sl = t >> 4, i = t & 15;
        const float* e = En + ((size_t)n * 4096 + c * 16 + sl) * 256 + i * 16;
        float a = 0.f;
        #pragma unroll
        for (int j = 0; j < 16; ++j)
            a += __expf((e[j] - sm[i * 16 + j]) * 0.125f) * sz[i * 16 + j];
        sa[sl * 16 + i] = a;
    }
    __syncthreads();

    // combine: thread owns 4 output cols o0..o0+3 across all 16 i-rows
    const int o0 = t * 4;
    const u16* gp = G + ((size_t)n * 4096 + c * 16) * 1024 + o0;
    f32x4 g[16];
    #pragma unroll
    for (int sl = 0; sl < 16; ++sl) {
        u16x4 gv = *(const u16x4*)&gp[(size_t)sl * 1024];
        g[sl][0] = bf2f(gv[0]); g[sl][1] = bf2f(gv[1]);
        g[sl][2] = bf2f(gv[2]); g[sl][3] = bf2f(gv[3]);
    }
    const f32x4 b4 = *(const f32x4*)&bo[o0];
    #pragma unroll
    for (int i = 0; i < 16; ++i) {
        f32x4 acc = b4;
        #pragma unroll
        for (int sl = 0; sl < 16; ++sl) {
            const float a = sa[sl * 16 + i];
            acc[0] += a * g[sl][0];
            acc[1] += a * g[sl][1];
            acc[2] += a * g[sl][2];
            acc[3] += a * g[sl][3];
        }
        *(f32x4*)&out[((size_t)n * 4096 + i * 256 + c) * 1024 + o0] = acc;
    }
}

// ---------------------------------------------------------------------------
extern "C" void kernel_launch(void* const* d_in, const int* in_sizes, int n_in,
                              void* d_out, int out_size, void* d_ws, size_t ws_size,
                              hipStream_t stream)
{
    const float* x  = (const float*)d_in[0];
    const float* Wq = (const float*)d_in[1];
    const float* Wk = (const float*)d_in[2];
    const float* Wv = (const float*)d_in[3];
    const float* Wo = (const float*)d_in[4];
    const float* bo = (const float*)d_in[5];
    float* out = (float*)d_out;
    char* ws = (char*)d_ws;

    u16*   xb   = (u16*)  (ws + OFF_XB);
    float* En   = (float*)(ws + OFF_EN);    // aliases xb (xb dead after gemm_vs)
    u16*   QKb  = (u16*)  (ws + OFF_QK);    // [16384][2048]: Q | K
    u16*   G    = (u16*)  (ws + OFF_QK);    // aliases QKb (dead after energy)
    u16*   Wqb  = (u16*)  (ws + OFF_WQB);   // [Wqb ; Wkb] contiguous = merged B
    u16*   Wkb  = (u16*)  (ws + OFF_WKB);
    u16*   Wob  = (u16*)  (ws + OFF_WOB);
    u16*   Bvs  = (u16*)  (ws + OFF_WVST);
    u16*   Vsb  = (u16*)  (ws + OFF_VS);
    float* gmax = (float*)(ws + OFF_GMAX);
    float* invZ = (float*)(ws + OFF_INVZ);
    float* pmax = (float*)(ws + OFF_ST);
    float* psum = (float*)(ws + OFF_ST + 262144);

    // 1. casts + head-reduced bf16 Wv
    cvt_kernel <<<9728, 256, 0, stream>>>(x, Wq, Wk, Wo, xb, Wqb, Wkb, Wob);
    wvst_kernel<<<256,  256, 0, stream>>>(Wv, Bvs);

    // 2. merged Q|K projection (256x128 tiles, 64x16=1024 blocks, 2/CU) + Vs
    gemm_qk<<<1024, 512, 0, stream>>>(xb, Wqb, QKb, 16384, 2048, 1024, 4);
    gemm_vs<<<256, 256, 0, stream>>>(xb, Bvs, Vsb);

    // 3. per-site 16x16 head-Gram energy (overwrites xb region)
    energy_kernel<<<4096, 256, 0, stream>>>(QKb, En);

    // 4. softmax-over-S stats (online, scratch-free)
    stats_part<<<256, 256, 0, stream>>>(En, pmax, psum);
    stats_comb<<<4,   256, 0, stream>>>(pmax, psum, gmax, invZ);

    // 5. G = Vs x Wo-slices (thin-K GEMM, bf16 out, overwrites QKb region)
    g_kernel<<<dim3(4, 16, 16), 256, 0, stream>>>(Vsb, Wob, G);

    // 6. fused A-compute + 16-term combine + bias -> fp32 d_out
    comb_kernel<<<1024, 256, 0, stream>>>(En, gmax, invZ, G, bo, out);
}

// Round 11
// 171.927 us; speedup vs baseline: 1.0909x; 1.0252x over previous
//
#include <hip/hip_runtime.h>
#include <stdint.h>

typedef unsigned short u16;
typedef unsigned int   u32;
typedef __attribute__((ext_vector_type(8))) short short8;
typedef __attribute__((ext_vector_type(4))) float f32x4;
typedef __attribute__((ext_vector_type(8))) u16   u16x8;
typedef __attribute__((ext_vector_type(4))) u16   u16x4;

// Problem constants: N=4, S=4096, E=1024, H=16, D=64
static constexpr size_t NX = (size_t)4 * 4096 * 1024;   // 16,777,216 x elems
static constexpr size_t NW = (size_t)1024 * 1024;       // 1,048,576 weight elems

// Workspace layout (bytes).
// OFF_XB: xb bf16 33.5MB, later En f32 16.8MB (xb dead after gemm_vs).
// OFF_QK: QKb bf16 67MB, later G bf16 33.5MB (QKb dead after energy).
static constexpr size_t OFF_XB   = 0;
static constexpr size_t OFF_EN   = 0;
static constexpr size_t OFF_QK   = 33554432;
static constexpr size_t OFF_WQB  = 100663296;           // 2,097,152 (Wkb contiguous after)
static constexpr size_t OFF_WKB  = 102760448;           // 2,097,152
static constexpr size_t OFF_WOB  = 104857600;           // 2,097,152
static constexpr size_t OFF_WVST = 106954752;           // 131,072  bf16 Bvs [64][1024]
static constexpr size_t OFF_VS   = 107216896;           // 2,097,152 bf16 Vsb [16384][64]
static constexpr size_t OFF_GMAX = 111411200;           // 4,096
static constexpr size_t OFF_INVZ = 111415296;           // 4,096
static constexpr size_t OFF_ST   = 111419392;           // pmax 256KB + psum 256KB

static __device__ __forceinline__ u16 f2bf(float f) {
    u32 u = __builtin_bit_cast(u32, f);
    u += 0x7fffu + ((u >> 16) & 1u);        // RNE
    return (u16)(u >> 16);
}
static __device__ __forceinline__ float bf2f(u16 v) {
    u32 u = ((u32)v) << 16;
    return __builtin_bit_cast(float, u);
}

#if __has_builtin(__builtin_amdgcn_global_load_lds)
#define HAVE_GLOAD_LDS 1
static __device__ __forceinline__ void gload_lds16(const void* g, void* l) {
    __builtin_amdgcn_global_load_lds(
        (__attribute__((address_space(1))) void*)(uintptr_t)g,
        (__attribute__((address_space(3))) void*)(uintptr_t)l,
        16, 0, 0);
}
#endif

#if __has_builtin(__builtin_amdgcn_sched_barrier)
#define SCHED_FENCE() __builtin_amdgcn_sched_barrier(0)
#else
#define SCHED_FENCE()
#endif

// ---------------------------------------------------------------------------
// fused fp32 -> bf16 conversion for x, Wq, Wk, Wo  PLUS head-reduced Wv
// (blocks 0..9727: elementwise cast; blocks 9728..9983: Bvs build).
__global__ __launch_bounds__(256)
void cvt_all_kernel(const float* __restrict__ x, const float* __restrict__ wq,
                    const float* __restrict__ wk, const float* __restrict__ wv,
                    const float* __restrict__ wo,
                    u16* __restrict__ xb, u16* __restrict__ wqb,
                    u16* __restrict__ wkb, u16* __restrict__ wob,
                    u16* __restrict__ Bvs)
{
    const int blk = blockIdx.x;
    if (blk < 9728) {
        size_t i = ((size_t)blk * 256 + threadIdx.x) * 8;
        const float* s; u16* dst; size_t o;
        if (i < NX) { s = x; dst = xb; o = i; }
        else {
            size_t r = i - NX;
            int w = (int)(r >> 20);             // NW = 2^20
            o = r & (NW - 1);
            s   = (w == 0) ? wq  : (w == 1) ? wk  : wo;
            dst = (w == 0) ? wqb : (w == 1) ? wkb : wob;
        }
        f32x4 a = *(const f32x4*)&s[o];
        f32x4 c = *(const f32x4*)&s[o + 4];
        u16x8 v;
        v[0]=f2bf(a[0]); v[1]=f2bf(a[1]); v[2]=f2bf(a[2]); v[3]=f2bf(a[3]);
        v[4]=f2bf(c[0]); v[5]=f2bf(c[1]); v[6]=f2bf(c[2]); v[7]=f2bf(c[3]);
        *(u16x8*)&dst[o] = v;
    } else {
        // Bvs[d][e] = bf16( sum_h Wv[(h*64+d)*1024 + e] )
        int idx = (blk - 9728) * 256 + threadIdx.x;   // 65536 total
        int d = idx >> 10;
        int e = idx & 1023;
        float s = 0.f;
        #pragma unroll
        for (int h = 0; h < 16; ++h) s += wv[(size_t)(h * 64 + d) * 1024 + e];
        Bvs[(size_t)d * 1024 + e] = f2bf(s);
    }
}

// ---------------------------------------------------------------------------
// 256x256-tile 8-wave bf16 GEMM, FREE-RUN schedule (R7, best measured 84.6us
// = 812 TF, within 4% of m248's documented K=1024 ceiling of 848 TF).
// One __syncthreads per K-tile (flip drain provides ordering); fragment
// reads issued quadrant-ahead in source order (compiler emits counted
// lgkmcnt); stages issued at tile top so loads age a full tile.
__global__ __launch_bounds__(512, 2)
void gemm_qk(const u16* __restrict__ A, const u16* __restrict__ Bw,
             u16* __restrict__ C, int M, int N, int K, int lognbx)
{
    __shared__ u16 lds[65536];              // [A: 2x16384][B: 2x16384] u16
    const int tid  = threadIdx.x;
    const int wave = tid >> 6;
    const int lane = tid & 63;

    const int nwg = gridDim.x;
    const int swz = ((int)blockIdx.x & 7) * (nwg >> 3) + ((int)blockIdx.x >> 3);
    const long col0 = (long)(swz & ((1 << lognbx) - 1)) * 256;
    const long row0 = (long)(swz >> lognbx) * 256;

    const int wr2 = wave >> 2;
    const int wc2 = wave & 3;
    const int fr  = lane & 15;
    const int kq  = lane >> 4;
    const int rxor = fr & 7;

    const int t255  = tid & 255;
    const int halfA = tid >> 8;
    const int gAsrc = (t255 & 7) ^ ((t255 >> 3) & 7);
    const u16* sA = A + (size_t)(row0 + halfA * 128 + (t255 >> 3)) * K + gAsrc * 8;
    const int dA = halfA * 8192 + t255 * 8;

    const int u  = (tid & 127) | ((tid >> 1) & 128);
    const int bh = (tid >> 7) & 1;
    const int gBsrc = (u & 7) ^ ((u >> 3) & 7);
    const u16* sB = Bw + (size_t)(col0 + bh * 128 + (u >> 3)) * K + gBsrc * 8;
    const int dB = bh * 8192 + u * 8;

    auto STAGE = [&](int buf, int k0) {
        #pragma unroll
        for (int l = 0; l < 4; ++l) {
#ifdef HAVE_GLOAD_LDS
            gload_lds16(sA + (size_t)l * 32 * K + k0, &lds[buf * 16384 + dA + l * 2048]);
            gload_lds16(sB + (size_t)l * 32 * K + k0, &lds[32768 + buf * 16384 + dB + l * 2048]);
#else
            *(short8*)&lds[buf * 16384 + dA + l * 2048] =
                *(const short8*)(sA + (size_t)l * 32 * K + k0);
            *(short8*)&lds[32768 + buf * 16384 + dB + l * 2048] =
                *(const short8*)(sB + (size_t)l * 32 * K + k0);
#endif
        }
    };

    f32x4 acc[8][4] = {};

    STAGE(0, 0);
    __syncthreads();

    const int nt = K >> 6;
    for (int t = 0; t < nt; ++t) {
        const int cur = t & 1;
        const int base  = cur * 16384;
        const int bbase = 32768 + cur * 16384;

        if (t + 1 < nt) STAGE(cur ^ 1, (t + 1) << 6);

        short8 af[4][2], ag[4][2], bf[2][2], bg[2][2];
        #pragma unroll
        for (int m = 0; m < 4; ++m) {
            const int row = wr2 * 128 + m * 16 + fr;
            #pragma unroll
            for (int kk = 0; kk < 2; ++kk)
                af[m][kk] = *(const short8*)&lds[base + row * 64 + (((kk << 2) | kq) ^ rxor) * 8];
        }
        #pragma unroll
        for (int n = 0; n < 2; ++n) {
            const int col = wc2 * 64 + n * 16 + fr;
            #pragma unroll
            for (int kk = 0; kk < 2; ++kk)
                bf[n][kk] = *(const short8*)&lds[bbase + col * 64 + (((kk << 2) | kq) ^ rxor) * 8];
        }
        #pragma unroll
        for (int m = 0; m < 4; ++m) {
            const int row = wr2 * 128 + 64 + m * 16 + fr;
            #pragma unroll
            for (int kk = 0; kk < 2; ++kk)
                ag[m][kk] = *(const short8*)&lds[base + row * 64 + (((kk << 2) | kq) ^ rxor) * 8];
        }
        SCHED_FENCE();

        __builtin_amdgcn_s_setprio(1);
        #pragma unroll
        for (int kk = 0; kk < 2; ++kk)
            #pragma unroll
            for (int m = 0; m < 4; ++m)
                #pragma unroll
                for (int n = 0; n < 2; ++n)
                    acc[m][n] = __builtin_amdgcn_mfma_f32_16x16x32_bf16(af[m][kk], bf[n][kk], acc[m][n], 0, 0, 0);
        __builtin_amdgcn_s_setprio(0);

        #pragma unroll
        for (int n = 0; n < 2; ++n) {
            const int col = wc2 * 64 + (n + 2) * 16 + fr;
            #pragma unroll
            for (int kk = 0; kk < 2; ++kk)
                bg[n][kk] = *(const short8*)&lds[bbase + col * 64 + (((kk << 2) | kq) ^ rxor) * 8];
        }
        SCHED_FENCE();

        __builtin_amdgcn_s_setprio(1);
        #pragma unroll
        for (int kk = 0; kk < 2; ++kk)
            #pragma unroll
            for (int m = 0; m < 4; ++m)
                #pragma unroll
                for (int n = 0; n < 2; ++n)
                    acc[m + 4][n] = __builtin_amdgcn_mfma_f32_16x16x32_bf16(ag[m][kk], bf[n][kk], acc[m + 4][n], 0, 0, 0);
        #pragma unroll
        for (int kk = 0; kk < 2; ++kk)
            #pragma unroll
            for (int m = 0; m < 4; ++m)
                #pragma unroll
                for (int n = 0; n < 2; ++n)
                    acc[m][n + 2] = __builtin_amdgcn_mfma_f32_16x16x32_bf16(af[m][kk], bg[n][kk], acc[m][n + 2], 0, 0, 0);
        #pragma unroll
        for (int kk = 0; kk < 2; ++kk)
            #pragma unroll
            for (int m = 0; m < 4; ++m)
                #pragma unroll
                for (int n = 0; n < 2; ++n)
                    acc[m + 4][n + 2] = __builtin_amdgcn_mfma_f32_16x16x32_bf16(ag[m][kk], bg[n][kk], acc[m + 4][n + 2], 0, 0, 0);
        __builtin_amdgcn_s_setprio(0);

        __syncthreads();
    }

    #pragma unroll
    for (int m = 0; m < 8; ++m) {
        #pragma unroll
        for (int n = 0; n < 4; ++n) {
            long gr = row0 + wr2 * 128 + m * 16 + kq * 4;
            long gc = col0 + wc2 * 64 + n * 16 + fr;
            #pragma unroll
            for (int j = 0; j < 4; ++j)
                C[(gr + j) * N + gc] = f2bf(acc[m][n][j]);
        }
    }
}

// ---------------------------------------------------------------------------
// Vsb = bf16( xb @ Bvs^T ) : M=16384, N=64, K=1024. 64x64 tile, 4 waves,
// 2-phase double-buffer. Grid = 256 blocks.
__global__ __launch_bounds__(256)
void gemm_vs(const u16* __restrict__ A, const u16* __restrict__ Bw,
             u16* __restrict__ C)
{
    __shared__ u16 lsA[2][64 * 32];
    __shared__ u16 lsB[2][64 * 32];
    const int tid  = threadIdx.x;
    const int wave = tid >> 6;
    const int lane = tid & 63;
    const long row0 = (long)blockIdx.x * 64;
    const int wr = (wave >> 1) * 32;
    const int wc = (wave & 1) * 32;
    const int fr = lane & 15;
    const int k8 = (lane >> 4) * 8;

    f32x4 acc[2][2] = {};
    const int c0 = tid;
    const u16* pa = &A [(row0 + (c0 >> 2)) * 1024 + (c0 & 3) * 8];
    const u16* pb = &Bw[((size_t)(c0 >> 2)) * 1024 + (c0 & 3) * 8];

    auto STAGE = [&](int buf, int k0) {
#ifdef HAVE_GLOAD_LDS
        gload_lds16(pa + k0, &lsA[buf][wave * 512]);
        gload_lds16(pb + k0, &lsB[buf][wave * 512]);
#else
        *(short8*)&lsA[buf][(size_t)c0 * 8] = *(const short8*)(pa + k0);
        *(short8*)&lsB[buf][(size_t)c0 * 8] = *(const short8*)(pb + k0);
#endif
    };

    STAGE(0, 0);
    __syncthreads();
    for (int t = 0; t < 32; ++t) {
        const int cur = t & 1;
        if (t + 1 < 32) STAGE(cur ^ 1, (t + 1) << 5);
        short8 af[2], bf[2];
        #pragma unroll
        for (int m = 0; m < 2; ++m)
            af[m] = *(const short8*)&lsA[cur][(wr + m * 16 + fr) * 32 + k8];
        #pragma unroll
        for (int n = 0; n < 2; ++n)
            bf[n] = *(const short8*)&lsB[cur][(wc + n * 16 + fr) * 32 + k8];
        #pragma unroll
        for (int m = 0; m < 2; ++m)
            #pragma unroll
            for (int n = 0; n < 2; ++n)
                acc[m][n] = __builtin_amdgcn_mfma_f32_16x16x32_bf16(af[m], bf[n], acc[m][n], 0, 0, 0);
        __syncthreads();
    }

    const int orow = (lane >> 4) * 4;
    #pragma unroll
    for (int m = 0; m < 2; ++m) {
        #pragma unroll
        for (int n = 0; n < 2; ++n) {
            long gr = row0 + wr + m * 16 + orow;
            int  gc = wc + n * 16 + fr;
            #pragma unroll
            for (int j = 0; j < 4; ++j)
                C[(gr + j) * 64 + gc] = f2bf(acc[m][n][j]);
        }
    }
}

// ---------------------------------------------------------------------------
// FUSED energy + softmax-stats: 256 blocks x 64 sites (16 sites/wave).
// Per site, per wave: 2 MFMA -> En[site][i*16+j]; each lane's 4 acc slots are
// the SAME (i,j) pairs (i=(lane>>4)*4+r, j=lane&15) across all its sites, so
// per-lane ONLINE (m,z) over 16 sites; cross-wave merge in LDS; writes the
// same pmax/psum layout stats_part produced (chunk b = 64 sites, p = i*16+j).
__global__ __launch_bounds__(256)
void energy_stats_kernel(const u16* __restrict__ QKb, float* __restrict__ E,
                         float* __restrict__ pmax, float* __restrict__ psum)
{
    __shared__ float red[4][64][8];     // [wave][lane][m0..3|z0..3]
    const int wave = threadIdx.x >> 6, lane = threadIdx.x & 63;
    const size_t s0 = (size_t)blockIdx.x * 64 + wave * 16;
    const int hh = lane & 15;
    const int kg = lane >> 4;
    float m[4] = {-3.4e38f, -3.4e38f, -3.4e38f, -3.4e38f};
    float z[4] = {0.f, 0.f, 0.f, 0.f};

    for (int s = 0; s < 16; ++s) {
        const u16* qrow = QKb + (s0 + s) * 2048;
        short8 a0 = *(const short8*)&qrow[hh * 64 + kg * 8];
        short8 a1 = *(const short8*)&qrow[hh * 64 + 32 + kg * 8];
        short8 b0 = *(const short8*)&qrow[1024 + hh * 64 + kg * 8];
        short8 b1 = *(const short8*)&qrow[1024 + hh * 64 + 32 + kg * 8];
        f32x4 acc = {};
        acc = __builtin_amdgcn_mfma_f32_16x16x32_bf16(a0, b0, acc, 0, 0, 0);
        acc = __builtin_amdgcn_mfma_f32_16x16x32_bf16(a1, b1, acc, 0, 0, 0);
        float* o = E + (s0 + s) * 256;
        #pragma unroll
        for (int r = 0; r < 4; ++r) {
            const float v = acc[r];
            o[(kg * 4 + r) * 16 + hh] = v;          // row=i, col=j
            const float mn = fmaxf(m[r], v);
            z[r] = z[r] * __expf((m[r] - mn) * 0.125f) + __expf((v - mn) * 0.125f);
            m[r] = mn;
        }
    }
    #pragma unroll
    for (int r = 0; r < 4; ++r) { red[wave][lane][r] = m[r]; red[wave][lane][4 + r] = z[r]; }
    __syncthreads();

    // final merge: thread t -> (i,j): i=t>>4, j=t&15; source lane=(i>>2)*16+j, r=i&3
    const int t = threadIdx.x;
    const int i = t >> 4, j = t & 15;
    const int ln = (i >> 2) * 16 + j, r = i & 3;
    float M = -3.4e38f, Z = 0.f;
    #pragma unroll
    for (int w = 0; w < 4; ++w) {
        const float mw = red[w][ln][r], zw = red[w][ln][4 + r];
        const float mn = fmaxf(M, mw);
        Z = Z * __expf((M - mn) * 0.125f) + zw * __expf((mw - mn) * 0.125f);
        M = mn;
    }
    pmax[blockIdx.x * 256 + t] = M;
    psum[blockIdx.x * 256 + t] = Z;
}

__global__ __launch_bounds__(256)
void stats_comb(const float* __restrict__ pmax, const float* __restrict__ psum,
                float* __restrict__ gmax, float* __restrict__ invZ)
{
    const int n = blockIdx.x, p = threadIdx.x;
    float m = -3.4e38f;
    for (int c = 0; c < 64; ++c) m = fmaxf(m, pmax[(n * 64 + c) * 256 + p]);
    float z = 0.f;
    for (int c = 0; c < 64; ++c)
        z += psum[(n * 64 + c) * 256 + p] * __expf((pmax[(n * 64 + c) * 256 + p] - m) * 0.125f);
    gmax[n * 256 + p] = m;
    invZ[n * 256 + p] = 1.0f / z;
}

// ---------------------------------------------------------------------------
// G[srow][o] = bf16( sum_d Vsb[srow][d] * Wob[o][64*(srow&15)+d] )
__global__ __launch_bounds__(256)
void g_kernel(const u16* __restrict__ Vsb, const u16* __restrict__ Wob,
              u16* __restrict__ G)
{
    __shared__ u16 lA[64 * 64];     // [j][k granule-swizzled] 8KB
    __shared__ u16 lB[256 * 64];    // [o'][k granule-swizzled] 32KB
    const int tid = threadIdx.x;
    const int wave = tid >> 6, lane = tid & 63;
    const int op = blockIdx.x, uc = blockIdx.y, sl = blockIdx.z;

    {   // stage A: 4 threads/row, 2 granules each
        const int j = tid >> 2;
        const size_t srow = (size_t)16 * (64 * uc + j) + sl;
        #pragma unroll
        for (int h = 0; h < 2; ++h) {
            const int g = (tid & 3) + h * 4;
            u16x8 v = *(const u16x8*)&Vsb[srow * 64 + g * 8];
            *(u16x8*)&lA[j * 64 + ((g ^ (j & 7)) * 8)] = v;
        }
    }
    {   // stage B: 1 row/thread, 8 granules
        const size_t o = (size_t)op * 256 + tid;
        #pragma unroll
        for (int g = 0; g < 8; ++g) {
            u16x8 v = *(const u16x8*)&Wob[o * 1024 + 64 * sl + g * 8];
            *(u16x8*)&lB[tid * 64 + ((g ^ (tid & 7)) * 8)] = v;
        }
    }
    __syncthreads();

    const int fr = lane & 15, kq = lane >> 4;
    f32x4 acc[4][4] = {};
    #pragma unroll
    for (int kk = 0; kk < 2; ++kk) {
        short8 af[4], bq[4];
        #pragma unroll
        for (int m = 0; m < 4; ++m) {
            const int j = m * 16 + fr;
            af[m] = *(const short8*)&lA[j * 64 + (((kq + 4 * kk) ^ (j & 7)) * 8)];
        }
        #pragma unroll
        for (int n = 0; n < 4; ++n) {
            const int o = wave * 64 + n * 16 + fr;
            bq[n] = *(const short8*)&lB[o * 64 + (((kq + 4 * kk) ^ (o & 7)) * 8)];
        }
        #pragma unroll
        for (int m = 0; m < 4; ++m)
            #pragma unroll
            for (int n = 0; n < 4; ++n)
                acc[m][n] = __builtin_amdgcn_mfma_f32_16x16x32_bf16(af[m], bq[n], acc[m][n], 0, 0, 0);
    }

    // C/D: col=lane&15, row=(lane>>4)*4+j  [m89]; tile-row -> srow stride 16
    #pragma unroll
    for (int m = 0; m < 4; ++m) {
        #pragma unroll
        for (int n = 0; n < 4; ++n) {
            const int ocol = op * 256 + wave * 64 + n * 16 + fr;
            #pragma unroll
            for (int jj = 0; jj < 4; ++jj) {
                const int j = m * 16 + kq * 4 + jj;
                G[((size_t)16 * (64 * uc + j) + sl) * 1024 + ocol] = f2bf(acc[m][n][jj]);
            }
        }
    }
}

// ---------------------------------------------------------------------------
// Fused A + combine: per block (n, c):
//   a[sl][i] = sum_j exp((En[n*4096+16c+sl][i*16+j]-gmax)*0.125)*invZ
//   out[n*4096 + i*256 + c][o] = bo[o] + sum_sl a[sl][i] * G[n*4096+16c+sl][o]
__global__ __launch_bounds__(256)
void comb_kernel(const float* __restrict__ En, const float* __restrict__ gmax,
                 const float* __restrict__ invZ, const u16* __restrict__ G,
                 const float* __restrict__ bo, float* __restrict__ out)
{
    __shared__ float sm[256], sz[256], sa[256];
    const int b = blockIdx.x;
    const int n = b >> 8, c = b & 255;
    const int t = threadIdx.x;
    sm[t] = gmax[n * 256 + t];
    sz[t] = invZ[n * 256 + t];
    __syncthreads();
    {   // a-part: t = sl*16 + i
        const int sl = t >> 4, i = t & 15;
        const float* e = En + ((size_t)n * 4096 + c * 16 + sl) * 256 + i * 16;
        float a = 0.f;
        #pragma unroll
        for (int j = 0; j < 16; ++j)
            a += __expf((e[j] - sm[i * 16 + j]) * 0.125f) * sz[i * 16 + j];
        sa[sl * 16 + i] = a;
    }
    __syncthreads();

    // combine: thread owns 4 output cols o0..o0+3 across all 16 i-rows
    const int o0 = t * 4;
    const u16* gp = G + ((size_t)n * 4096 + c * 16) * 1024 + o0;
    f32x4 g[16];
    #pragma unroll
    for (int sl = 0; sl < 16; ++sl) {
        u16x4 gv = *(const u16x4*)&gp[(size_t)sl * 1024];
        g[sl][0] = bf2f(gv[0]); g[sl][1] = bf2f(gv[1]);
        g[sl][2] = bf2f(gv[2]); g[sl][3] = bf2f(gv[3]);
    }
    const f32x4 b4 = *(const f32x4*)&bo[o0];
    #pragma unroll
    for (int i = 0; i < 16; ++i) {
        f32x4 acc = b4;
        #pragma unroll
        for (int sl = 0; sl < 16; ++sl) {
            const float a = sa[sl * 16 + i];
            acc[0] += a * g[sl][0];
            acc[1] += a * g[sl][1];
            acc[2] += a * g[sl][2];
            acc[3] += a * g[sl][3];
        }
        *(f32x4*)&out[((size_t)n * 4096 + i * 256 + c) * 1024 + o0] = acc;
    }
}

// ---------------------------------------------------------------------------
extern "C" void kernel_launch(void* const* d_in, const int* in_sizes, int n_in,
                              void* d_out, int out_size, void* d_ws, size_t ws_size,
                              hipStream_t stream)
{
    const float* x  = (const float*)d_in[0];
    const float* Wq = (const float*)d_in[1];
    const float* Wk = (const float*)d_in[2];
    const float* Wv = (const float*)d_in[3];
    const float* Wo = (const float*)d_in[4];
    const float* bo = (const float*)d_in[5];
    float* out = (float*)d_out;
    char* ws = (char*)d_ws;

    u16*   xb   = (u16*)  (ws + OFF_XB);
    float* En   = (float*)(ws + OFF_EN);    // aliases xb (xb dead after gemm_vs)
    u16*   QKb  = (u16*)  (ws + OFF_QK);    // [16384][2048]: Q | K
    u16*   G    = (u16*)  (ws + OFF_QK);    // aliases QKb (dead after energy)
    u16*   Wqb  = (u16*)  (ws + OFF_WQB);   // [Wqb ; Wkb] contiguous = merged B
    u16*   Wkb  = (u16*)  (ws + OFF_WKB);
    u16*   Wob  = (u16*)  (ws + OFF_WOB);
    u16*   Bvs  = (u16*)  (ws + OFF_WVST);
    u16*   Vsb  = (u16*)  (ws + OFF_VS);
    float* gmax = (float*)(ws + OFF_GMAX);
    float* invZ = (float*)(ws + OFF_INVZ);
    float* pmax = (float*)(ws + OFF_ST);
    float* psum = (float*)(ws + OFF_ST + 262144);

    // 1. casts (x, Wq, Wk, Wo) + head-reduced bf16 Wv, one launch
    cvt_all_kernel<<<9984, 256, 0, stream>>>(x, Wq, Wk, Wv, Wo, xb, Wqb, Wkb, Wob, Bvs);

    // 2. merged Q|K projection (free-run 256x256, best measured) + Vs
    gemm_qk<<<512, 512, 0, stream>>>(xb, Wqb, QKb, 16384, 2048, 1024, 3);
    gemm_vs<<<256, 256, 0, stream>>>(xb, Bvs, Vsb);

    // 3. fused per-site energy + chunk softmax stats (overwrites xb region)
    energy_stats_kernel<<<256, 256, 0, stream>>>(QKb, En, pmax, psum);
    stats_comb<<<4, 256, 0, stream>>>(pmax, psum, gmax, invZ);

    // 4. G = Vs x Wo-slices (thin-K GEMM, bf16 out, overwrites QKb region)
    g_kernel<<<dim3(4, 16, 16), 256, 0, stream>>>(Vsb, Wob, G);

    // 5. fused A-compute + 16-term combine + bias -> fp32 d_out
    comb_kernel<<<1024, 256, 0, stream>>>(En, gmax, invZ, G, bo, out);
}

// Round 12
// 162.893 us; speedup vs baseline: 1.1514x; 1.0555x over previous
//
#include <hip/hip_runtime.h>
#include <stdint.h>

typedef unsigned short u16;
typedef unsigned int   u32;
typedef __attribute__((ext_vector_type(8))) short short8;
typedef __attribute__((ext_vector_type(4))) float f32x4;
typedef __attribute__((ext_vector_type(8))) u16   u16x8;
typedef __attribute__((ext_vector_type(4))) u16   u16x4;

// Problem constants: N=4, S=4096, E=1024, H=16, D=64
static constexpr size_t NX = (size_t)4 * 4096 * 1024;   // 16,777,216 x elems
static constexpr size_t NW = (size_t)1024 * 1024;       // 1,048,576 weight elems

// Workspace layout (bytes). Peak 112,467,968 < R0-proven 112,599,040.
static constexpr size_t OFF_XB   = 0;                   // xb bf16 33.5MB -> En f32 16.8MB
static constexpr size_t OFF_QK   = 33554432;            // QKb bf16 67MB -> G bf16 33.5MB
static constexpr size_t OFF_WQB  = 100663296;           // 2,097,152 (Wkb contiguous after)
static constexpr size_t OFF_WKB  = 102760448;
static constexpr size_t OFF_WOB  = 104857600;
static constexpr size_t OFF_WVST = 106954752;           // 131,072  bf16 Bvs [64][1024]
static constexpr size_t OFF_VS   = 107216896;           // 2,097,152 bf16 Vsb [16384][64]
static constexpr size_t OFF_GMAX = 111411200;           // 4,096
static constexpr size_t OFF_INVZ = 111415296;           // 4,096
static constexpr size_t OFF_ST   = 111419392;           // pmax 512KB + psum 512KB (512 chunks)

static __device__ __forceinline__ u16 f2bf(float f) {
    u32 u = __builtin_bit_cast(u32, f);
    u += 0x7fffu + ((u >> 16) & 1u);        // RNE
    return (u16)(u >> 16);
}
static __device__ __forceinline__ float bf2f(u16 v) {
    u32 u = ((u32)v) << 16;
    return __builtin_bit_cast(float, u);
}

#if __has_builtin(__builtin_amdgcn_global_load_lds)
#define HAVE_GLOAD_LDS 1
static __device__ __forceinline__ void gload_lds16(const void* g, void* l) {
    __builtin_amdgcn_global_load_lds(
        (__attribute__((address_space(1))) void*)(uintptr_t)g,
        (__attribute__((address_space(3))) void*)(uintptr_t)l,
        16, 0, 0);
}
#endif

#if __has_builtin(__builtin_amdgcn_sched_barrier)
#define SCHED_FENCE() __builtin_amdgcn_sched_barrier(0)
#else
#define SCHED_FENCE()
#endif

// ---------------------------------------------------------------------------
// fused fp32 -> bf16 conversion for x, Wq, Wk, Wo  PLUS head-reduced Wv
__global__ __launch_bounds__(256)
void cvt_all_kernel(const float* __restrict__ x, const float* __restrict__ wq,
                    const float* __restrict__ wk, const float* __restrict__ wv,
                    const float* __restrict__ wo,
                    u16* __restrict__ xb, u16* __restrict__ wqb,
                    u16* __restrict__ wkb, u16* __restrict__ wob,
                    u16* __restrict__ Bvs)
{
    const int blk = blockIdx.x;
    if (blk < 9728) {
        size_t i = ((size_t)blk * 256 + threadIdx.x) * 8;
        const float* s; u16* dst; size_t o;
        if (i < NX) { s = x; dst = xb; o = i; }
        else {
            size_t r = i - NX;
            int w = (int)(r >> 20);             // NW = 2^20
            o = r & (NW - 1);
            s   = (w == 0) ? wq  : (w == 1) ? wk  : wo;
            dst = (w == 0) ? wqb : (w == 1) ? wkb : wob;
        }
        f32x4 a = *(const f32x4*)&s[o];
        f32x4 c = *(const f32x4*)&s[o + 4];
        u16x8 v;
        v[0]=f2bf(a[0]); v[1]=f2bf(a[1]); v[2]=f2bf(a[2]); v[3]=f2bf(a[3]);
        v[4]=f2bf(c[0]); v[5]=f2bf(c[1]); v[6]=f2bf(c[2]); v[7]=f2bf(c[3]);
        *(u16x8*)&dst[o] = v;
    } else {
        // Bvs[d][e] = bf16( sum_h Wv[(h*64+d)*1024 + e] )
        int idx = (blk - 9728) * 256 + threadIdx.x;   // 65536 total
        int d = idx >> 10;
        int e = idx & 1023;
        float s = 0.f;
        #pragma unroll
        for (int h = 0; h < 16; ++h) s += wv[(size_t)(h * 64 + d) * 1024 + e];
        Bvs[(size_t)d * 1024 + e] = f2bf(s);
    }
}

// ---------------------------------------------------------------------------
// 256x256-tile 8-wave bf16 GEMM, FREE-RUN schedule (best measured: 84.6us
// = 812 TF, 96% of m248's documented K=1024 structural ceiling). FROZEN.
__global__ __launch_bounds__(512, 2)
void gemm_qk(const u16* __restrict__ A, const u16* __restrict__ Bw,
             u16* __restrict__ C, int M, int N, int K, int lognbx)
{
    __shared__ u16 lds[65536];              // [A: 2x16384][B: 2x16384] u16
    const int tid  = threadIdx.x;
    const int wave = tid >> 6;
    const int lane = tid & 63;

    const int nwg = gridDim.x;
    const int swz = ((int)blockIdx.x & 7) * (nwg >> 3) + ((int)blockIdx.x >> 3);
    const long col0 = (long)(swz & ((1 << lognbx) - 1)) * 256;
    const long row0 = (long)(swz >> lognbx) * 256;

    const int wr2 = wave >> 2;
    const int wc2 = wave & 3;
    const int fr  = lane & 15;
    const int kq  = lane >> 4;
    const int rxor = fr & 7;

    const int t255  = tid & 255;
    const int halfA = tid >> 8;
    const int gAsrc = (t255 & 7) ^ ((t255 >> 3) & 7);
    const u16* sA = A + (size_t)(row0 + halfA * 128 + (t255 >> 3)) * K + gAsrc * 8;
    const int dA = halfA * 8192 + t255 * 8;

    const int u  = (tid & 127) | ((tid >> 1) & 128);
    const int bh = (tid >> 7) & 1;
    const int gBsrc = (u & 7) ^ ((u >> 3) & 7);
    const u16* sB = Bw + (size_t)(col0 + bh * 128 + (u >> 3)) * K + gBsrc * 8;
    const int dB = bh * 8192 + u * 8;

    auto STAGE = [&](int buf, int k0) {
        #pragma unroll
        for (int l = 0; l < 4; ++l) {
#ifdef HAVE_GLOAD_LDS
            gload_lds16(sA + (size_t)l * 32 * K + k0, &lds[buf * 16384 + dA + l * 2048]);
            gload_lds16(sB + (size_t)l * 32 * K + k0, &lds[32768 + buf * 16384 + dB + l * 2048]);
#else
            *(short8*)&lds[buf * 16384 + dA + l * 2048] =
                *(const short8*)(sA + (size_t)l * 32 * K + k0);
            *(short8*)&lds[32768 + buf * 16384 + dB + l * 2048] =
                *(const short8*)(sB + (size_t)l * 32 * K + k0);
#endif
        }
    };

    f32x4 acc[8][4] = {};

    STAGE(0, 0);
    __syncthreads();

    const int nt = K >> 6;
    for (int t = 0; t < nt; ++t) {
        const int cur = t & 1;
        const int base  = cur * 16384;
        const int bbase = 32768 + cur * 16384;

        if (t + 1 < nt) STAGE(cur ^ 1, (t + 1) << 6);

        short8 af[4][2], ag[4][2], bf[2][2], bg[2][2];
        #pragma unroll
        for (int m = 0; m < 4; ++m) {
            const int row = wr2 * 128 + m * 16 + fr;
            #pragma unroll
            for (int kk = 0; kk < 2; ++kk)
                af[m][kk] = *(const short8*)&lds[base + row * 64 + (((kk << 2) | kq) ^ rxor) * 8];
        }
        #pragma unroll
        for (int n = 0; n < 2; ++n) {
            const int col = wc2 * 64 + n * 16 + fr;
            #pragma unroll
            for (int kk = 0; kk < 2; ++kk)
                bf[n][kk] = *(const short8*)&lds[bbase + col * 64 + (((kk << 2) | kq) ^ rxor) * 8];
        }
        #pragma unroll
        for (int m = 0; m < 4; ++m) {
            const int row = wr2 * 128 + 64 + m * 16 + fr;
            #pragma unroll
            for (int kk = 0; kk < 2; ++kk)
                ag[m][kk] = *(const short8*)&lds[base + row * 64 + (((kk << 2) | kq) ^ rxor) * 8];
        }
        SCHED_FENCE();

        __builtin_amdgcn_s_setprio(1);
        #pragma unroll
        for (int kk = 0; kk < 2; ++kk)
            #pragma unroll
            for (int m = 0; m < 4; ++m)
                #pragma unroll
                for (int n = 0; n < 2; ++n)
                    acc[m][n] = __builtin_amdgcn_mfma_f32_16x16x32_bf16(af[m][kk], bf[n][kk], acc[m][n], 0, 0, 0);
        __builtin_amdgcn_s_setprio(0);

        #pragma unroll
        for (int n = 0; n < 2; ++n) {
            const int col = wc2 * 64 + (n + 2) * 16 + fr;
            #pragma unroll
            for (int kk = 0; kk < 2; ++kk)
                bg[n][kk] = *(const short8*)&lds[bbase + col * 64 + (((kk << 2) | kq) ^ rxor) * 8];
        }
        SCHED_FENCE();

        __builtin_amdgcn_s_setprio(1);
        #pragma unroll
        for (int kk = 0; kk < 2; ++kk)
            #pragma unroll
            for (int m = 0; m < 4; ++m)
                #pragma unroll
                for (int n = 0; n < 2; ++n)
                    acc[m + 4][n] = __builtin_amdgcn_mfma_f32_16x16x32_bf16(ag[m][kk], bf[n][kk], acc[m + 4][n], 0, 0, 0);
        #pragma unroll
        for (int kk = 0; kk < 2; ++kk)
            #pragma unroll
            for (int m = 0; m < 4; ++m)
                #pragma unroll
                for (int n = 0; n < 2; ++n)
                    acc[m][n + 2] = __builtin_amdgcn_mfma_f32_16x16x32_bf16(af[m][kk], bg[n][kk], acc[m][n + 2], 0, 0, 0);
        #pragma unroll
        for (int kk = 0; kk < 2; ++kk)
            #pragma unroll
            for (int m = 0; m < 4; ++m)
                #pragma unroll
                for (int n = 0; n < 2; ++n)
                    acc[m + 4][n + 2] = __builtin_amdgcn_mfma_f32_16x16x32_bf16(ag[m][kk], bg[n][kk], acc[m + 4][n + 2], 0, 0, 0);
        __builtin_amdgcn_s_setprio(0);

        __syncthreads();
    }

    #pragma unroll
    for (int m = 0; m < 8; ++m) {
        #pragma unroll
        for (int n = 0; n < 4; ++n) {
            long gr = row0 + wr2 * 128 + m * 16 + kq * 4;
            long gc = col0 + wc2 * 64 + n * 16 + fr;
            #pragma unroll
            for (int j = 0; j < 4; ++j)
                C[(gr + j) * N + gc] = f2bf(acc[m][n][j]);
        }
    }
}

// ---------------------------------------------------------------------------
// Vsb = bf16( xb @ Bvs^T ) : M=16384, N=64, K=1024. 64x64 tile, BK=32,
// 8 waves (wave tile 16x32): waves 0-3 stage A, 4-7 stage B; 2x parallelism
// vs R11 (8 waves/CU). Granule swizzle (row>>1)&3 on stage-source and read
// (R10-verified involution for 64B rows) -> 2-way max conflicts.
__global__ __launch_bounds__(512)
void gemm_vs(const u16* __restrict__ A, const u16* __restrict__ Bw,
             u16* __restrict__ C)
{
    __shared__ u16 lsA[2][64 * 32];
    __shared__ u16 lsB[2][64 * 32];
    const int tid  = threadIdx.x;
    const int wave = tid >> 6;              // 0..7
    const int lane = tid & 63;
    const long row0 = (long)blockIdx.x * 64;
    const int wr = (wave >> 1) * 16;        // 4 row groups of 16
    const int wc = (wave & 1) * 32;         // 2 col groups of 32
    const int fr = lane & 15;
    const int kq = lane >> 4;
    const int rx = (fr >> 1) & 3;

    f32x4 acc[2] = {};
    const int g = tid & 255;                // granule id within matrix
    const int grow = g >> 2;
    const int gsw  = (g & 3) ^ ((grow >> 1) & 3);
    const bool isA = tid < 256;
    const u16* src = isA ? &A [(row0 + grow) * 1024 + gsw * 8]
                         : &Bw[((size_t)grow) * 1024 + gsw * 8];

    auto STAGE = [&](int buf, int k0) {
#ifdef HAVE_GLOAD_LDS
        if (isA) gload_lds16(src + k0, &lsA[buf][wave * 512]);
        else     gload_lds16(src + k0, &lsB[buf][(wave - 4) * 512]);
#else
        if (isA) *(short8*)&lsA[buf][(size_t)g * 8] = *(const short8*)(src + k0);
        else     *(short8*)&lsB[buf][(size_t)g * 8] = *(const short8*)(src + k0);
#endif
    };

    STAGE(0, 0);
    __syncthreads();
    for (int t = 0; t < 32; ++t) {
        const int cur = t & 1;
        if (t + 1 < 32) STAGE(cur ^ 1, (t + 1) << 5);
        short8 af, bf[2];
        af = *(const short8*)&lsA[cur][(wr + fr) * 32 + ((kq ^ rx) * 8)];
        #pragma unroll
        for (int n = 0; n < 2; ++n)
            bf[n] = *(const short8*)&lsB[cur][(wc + n * 16 + fr) * 32 + ((kq ^ rx) * 8)];
        #pragma unroll
        for (int n = 0; n < 2; ++n)
            acc[n] = __builtin_amdgcn_mfma_f32_16x16x32_bf16(af, bf[n], acc[n], 0, 0, 0);
        __syncthreads();
    }

    const int orow = kq * 4;
    #pragma unroll
    for (int n = 0; n < 2; ++n) {
        #pragma unroll
        for (int j = 0; j < 4; ++j)
            C[(row0 + wr + orow + j) * 64 + wc + n * 16 + fr] = f2bf(acc[n][j]);
    }
}

// ---------------------------------------------------------------------------
// FUSED energy + softmax-stats: 512 blocks x 32 sites (8 sites/wave) ->
// 2 blocks/CU, 8 waves/CU (2x R11's parallelism). Chunk = 32 sites;
// pmax/psum layout [512][256], p = i*16+j.
__global__ __launch_bounds__(256)
void energy_stats_kernel(const u16* __restrict__ QKb, float* __restrict__ E,
                         float* __restrict__ pmax, float* __restrict__ psum)
{
    __shared__ float red[4][64][8];     // [wave][lane][m0..3|z0..3]
    const int wave = threadIdx.x >> 6, lane = threadIdx.x & 63;
    const size_t s0 = (size_t)blockIdx.x * 32 + wave * 8;
    const int hh = lane & 15;
    const int kg = lane >> 4;
    float m[4] = {-3.4e38f, -3.4e38f, -3.4e38f, -3.4e38f};
    float z[4] = {0.f, 0.f, 0.f, 0.f};

    for (int s = 0; s < 8; ++s) {
        const u16* qrow = QKb + (s0 + s) * 2048;
        short8 a0 = *(const short8*)&qrow[hh * 64 + kg * 8];
        short8 a1 = *(const short8*)&qrow[hh * 64 + 32 + kg * 8];
        short8 b0 = *(const short8*)&qrow[1024 + hh * 64 + kg * 8];
        short8 b1 = *(const short8*)&qrow[1024 + hh * 64 + 32 + kg * 8];
        f32x4 acc = {};
        acc = __builtin_amdgcn_mfma_f32_16x16x32_bf16(a0, b0, acc, 0, 0, 0);
        acc = __builtin_amdgcn_mfma_f32_16x16x32_bf16(a1, b1, acc, 0, 0, 0);
        float* o = E + (s0 + s) * 256;
        #pragma unroll
        for (int r = 0; r < 4; ++r) {
            const float v = acc[r];
            o[(kg * 4 + r) * 16 + hh] = v;          // row=i, col=j
            const float mn = fmaxf(m[r], v);
            z[r] = z[r] * __expf((m[r] - mn) * 0.125f) + __expf((v - mn) * 0.125f);
            m[r] = mn;
        }
    }
    #pragma unroll
    for (int r = 0; r < 4; ++r) { red[wave][lane][r] = m[r]; red[wave][lane][4 + r] = z[r]; }
    __syncthreads();

    // final merge: thread t -> (i,j): i=t>>4, j=t&15; source lane=(i>>2)*16+j, r=i&3
    const int t = threadIdx.x;
    const int i = t >> 4, j = t & 15;
    const int ln = (i >> 2) * 16 + j, r = i & 3;
    float M = -3.4e38f, Z = 0.f;
    #pragma unroll
    for (int w = 0; w < 4; ++w) {
        const float mw = red[w][ln][r], zw = red[w][ln][4 + r];
        const float mn = fmaxf(M, mw);
        Z = Z * __expf((M - mn) * 0.125f) + zw * __expf((mw - mn) * 0.125f);
        M = mn;
    }
    pmax[blockIdx.x * 256 + t] = M;
    psum[blockIdx.x * 256 + t] = Z;
}

// 4-way ILP merge over 128 chunks per n (chain depth 32, batched loads).
__global__ __launch_bounds__(256)
void stats_comb(const float* __restrict__ pmax, const float* __restrict__ psum,
                float* __restrict__ gmax, float* __restrict__ invZ)
{
    const int n = blockIdx.x, p = threadIdx.x;
    const float* pm = pmax + (size_t)n * 128 * 256 + p;
    const float* ps = psum + (size_t)n * 128 * 256 + p;
    float m[4] = {-3.4e38f, -3.4e38f, -3.4e38f, -3.4e38f};
    for (int c = 0; c < 32; ++c) {
        #pragma unroll
        for (int u = 0; u < 4; ++u)
            m[u] = fmaxf(m[u], pm[(size_t)(c + u * 32) * 256]);
    }
    const float M = fmaxf(fmaxf(m[0], m[1]), fmaxf(m[2], m[3]));
    float z[4] = {0.f, 0.f, 0.f, 0.f};
    for (int c = 0; c < 32; ++c) {
        #pragma unroll
        for (int u = 0; u < 4; ++u)
            z[u] += ps[(size_t)(c + u * 32) * 256] *
                    __expf((pm[(size_t)(c + u * 32) * 256] - M) * 0.125f);
    }
    gmax[n * 256 + p] = M;
    invZ[n * 256 + p] = 1.0f / (z[0] + z[1] + z[2] + z[3]);
}

// ---------------------------------------------------------------------------
// G[srow][o] = bf16( sum_d Vsb[srow][d] * Wob[o][64*(srow&15)+d] )
__global__ __launch_bounds__(256)
void g_kernel(const u16* __restrict__ Vsb, const u16* __restrict__ Wob,
              u16* __restrict__ G)
{
    __shared__ u16 lA[64 * 64];     // [j][k granule-swizzled] 8KB
    __shared__ u16 lB[256 * 64];    // [o'][k granule-swizzled] 32KB
    const int tid = threadIdx.x;
    const int wave = tid >> 6, lane = tid & 63;
    const int op = blockIdx.x, uc = blockIdx.y, sl = blockIdx.z;

    {   // stage A: 4 threads/row, 2 granules each
        const int j = tid >> 2;
        const size_t srow = (size_t)16 * (64 * uc + j) + sl;
        #pragma unroll
        for (int h = 0; h < 2; ++h) {
            const int g = (tid & 3) + h * 4;
            u16x8 v = *(const u16x8*)&Vsb[srow * 64 + g * 8];
            *(u16x8*)&lA[j * 64 + ((g ^ (j & 7)) * 8)] = v;
        }
    }
    {   // stage B: 1 row/thread, 8 granules
        const size_t o = (size_t)op * 256 + tid;
        #pragma unroll
        for (int g = 0; g < 8; ++g) {
            u16x8 v = *(const u16x8*)&Wob[o * 1024 + 64 * sl + g * 8];
            *(u16x8*)&lB[tid * 64 + ((g ^ (tid & 7)) * 8)] = v;
        }
    }
    __syncthreads();

    const int fr = lane & 15, kq = lane >> 4;
    f32x4 acc[4][4] = {};
    #pragma unroll
    for (int kk = 0; kk < 2; ++kk) {
        short8 af[4], bq[4];
        #pragma unroll
        for (int m = 0; m < 4; ++m) {
            const int j = m * 16 + fr;
            af[m] = *(const short8*)&lA[j * 64 + (((kq + 4 * kk) ^ (j & 7)) * 8)];
        }
        #pragma unroll
        for (int n = 0; n < 4; ++n) {
            const int o = wave * 64 + n * 16 + fr;
            bq[n] = *(const short8*)&lB[o * 64 + (((kq + 4 * kk) ^ (o & 7)) * 8)];
        }
        #pragma unroll
        for (int m = 0; m < 4; ++m)
            #pragma unroll
            for (int n = 0; n < 4; ++n)
                acc[m][n] = __builtin_amdgcn_mfma_f32_16x16x32_bf16(af[m], bq[n], acc[m][n], 0, 0, 0);
    }

    // C/D: col=lane&15, row=(lane>>4)*4+j  [m89]; tile-row -> srow stride 16
    #pragma unroll
    for (int m = 0; m < 4; ++m) {
        #pragma unroll
        for (int n = 0; n < 4; ++n) {
            const int ocol = op * 256 + wave * 64 + n * 16 + fr;
            #pragma unroll
            for (int jj = 0; jj < 4; ++jj) {
                const int j = m * 16 + kq * 4 + jj;
                G[((size_t)16 * (64 * uc + j) + sl) * 1024 + ocol] = f2bf(acc[m][n][jj]);
            }
        }
    }
}

// ---------------------------------------------------------------------------
// Fused A + combine: per block (n, c):
//   a[sl][i] = sum_j exp((En[n*4096+16c+sl][i*16+j]-gmax)*0.125)*invZ
//   out[n*4096 + i*256 + c][o] = bo[o] + sum_sl a[sl][i] * G[n*4096+16c+sl][o]
__global__ __launch_bounds__(256)
void comb_kernel(const float* __restrict__ En, const float* __restrict__ gmax,
                 const float* __restrict__ invZ, const u16* __restrict__ G,
                 const float* __restrict__ bo, float* __restrict__ out)
{
    __shared__ float sm[256], sz[256], sa[256];
    const int b = blockIdx.x;
    const int n = b >> 8, c = b & 255;
    const int t = threadIdx.x;
    sm[t] = gmax[n * 256 + t];
    sz[t] = invZ[n * 256 + t];
    __syncthreads();
    {   // a-part: t = sl*16 + i
        const int sl = t >> 4, i = t & 15;
        const float* e = En + ((size_t)n * 4096 + c * 16 + sl) * 256 + i * 16;
        float a = 0.f;
        #pragma unroll
        for (int j = 0; j < 16; ++j)
            a += __expf((e[j] - sm[i * 16 + j]) * 0.125f) * sz[i * 16 + j];
        sa[sl * 16 + i] = a;
    }
    __syncthreads();

    // combine: thread owns 4 output cols o0..o0+3 across all 16 i-rows
    const int o0 = t * 4;
    const u16* gp = G + ((size_t)n * 4096 + c * 16) * 1024 + o0;
    f32x4 g[16];
    #pragma unroll
    for (int sl = 0; sl < 16; ++sl) {
        u16x4 gv = *(const u16x4*)&gp[(size_t)sl * 1024];
        g[sl][0] = bf2f(gv[0]); g[sl][1] = bf2f(gv[1]);
        g[sl][2] = bf2f(gv[2]); g[sl][3] = bf2f(gv[3]);
    }
    const f32x4 b4 = *(const f32x4*)&bo[o0];
    #pragma unroll
    for (int i = 0; i < 16; ++i) {
        f32x4 acc = b4;
        #pragma unroll
        for (int sl = 0; sl < 16; ++sl) {
            const float a = sa[sl * 16 + i];
            acc[0] += a * g[sl][0];
            acc[1] += a * g[sl][1];
            acc[2] += a * g[sl][2];
            acc[3] += a * g[sl][3];
        }
        *(f32x4*)&out[((size_t)n * 4096 + i * 256 + c) * 1024 + o0] = acc;
    }
}

// ---------------------------------------------------------------------------
extern "C" void kernel_launch(void* const* d_in, const int* in_sizes, int n_in,
                              void* d_out, int out_size, void* d_ws, size_t ws_size,
                              hipStream_t stream)
{
    const float* x  = (const float*)d_in[0];
    const float* Wq = (const float*)d_in[1];
    const float* Wk = (const float*)d_in[2];
    const float* Wv = (const float*)d_in[3];
    const float* Wo = (const float*)d_in[4];
    const float* bo = (const float*)d_in[5];
    float* out = (float*)d_out;
    char* ws = (char*)d_ws;

    u16*   xb   = (u16*)  (ws + OFF_XB);
    float* En   = (float*)(ws + OFF_XB);    // aliases xb (xb dead after gemm_vs)
    u16*   QKb  = (u16*)  (ws + OFF_QK);    // [16384][2048]: Q | K
    u16*   G    = (u16*)  (ws + OFF_QK);    // aliases QKb (dead after energy)
    u16*   Wqb  = (u16*)  (ws + OFF_WQB);   // [Wqb ; Wkb] contiguous = merged B
    u16*   Wkb  = (u16*)  (ws + OFF_WKB);
    u16*   Wob  = (u16*)  (ws + OFF_WOB);
    u16*   Bvs  = (u16*)  (ws + OFF_WVST);
    u16*   Vsb  = (u16*)  (ws + OFF_VS);
    float* gmax = (float*)(ws + OFF_GMAX);
    float* invZ = (float*)(ws + OFF_INVZ);
    float* pmax = (float*)(ws + OFF_ST);
    float* psum = (float*)(ws + OFF_ST + 524288);

    // 1. casts (x, Wq, Wk, Wo) + head-reduced bf16 Wv, one launch
    cvt_all_kernel<<<9984, 256, 0, stream>>>(x, Wq, Wk, Wv, Wo, xb, Wqb, Wkb, Wob, Bvs);

    // 2. merged Q|K projection (free-run 256x256, frozen) + Vs (8-wave)
    gemm_qk<<<512, 512, 0, stream>>>(xb, Wqb, QKb, 16384, 2048, 1024, 3);
    gemm_vs<<<256, 512, 0, stream>>>(xb, Bvs, Vsb);

    // 3. fused per-site energy + chunk softmax stats (512 blocks, 2/CU)
    energy_stats_kernel<<<512, 256, 0, stream>>>(QKb, En, pmax, psum);
    stats_comb<<<4, 256, 0, stream>>>(pmax, psum, gmax, invZ);

    // 4. G = Vs x Wo-slices (thin-K GEMM, bf16 out, overwrites QKb region)
    g_kernel<<<dim3(4, 16, 16), 256, 0, stream>>>(Vsb, Wob, G);

    // 5. fused A-compute + 16-term combine + bias -> fp32 d_out
    comb_kernel<<<1024, 256, 0, stream>>>(En, gmax, invZ, G, bo, out);
}